// Round 9
// baseline (450.015 us; speedup 1.0000x reference)
//
#include <hip/hip_runtime.h>
#include <hip/hip_fp16.h>

// Problem constants
constexpr int NN   = 50000;
constexpr int EE   = 800000;
constexpr int INF  = 128;   // input feat
constexpr int NH   = 4;     // heads
constexpr int GR64 = (NN + 63) / 64;        // 782 row tiles (64-row GEMM tiling)
constexpr int EB   = (EE + 255) / 256;      // 3125 edge blocks
constexpr int NCH  = (NN + 255) / 256;      // 196 scan chunks

struct __align__(8) h4 { __half2 a, b; };   // 4 halves = 8 bytes

__device__ __forceinline__ float elw(float a) {
    a = (a > 0.f) ? a : 0.2f * a;          // leaky_relu(0.2)
    return __expf(a);                       // exp without max-sub (scores bounded)
}

// ======== 64x128 tile fp32 GEMM, BK=32, 4 rows x (4+4 split) cols per thread ========
// BK=32 halves the barrier count vs BK=16: per barrier-interval 2048 VALU-cyc of FMA
// against one staging round -> staging latency amortizes 2x. Same per-thread k-order
// as BK=16 (bit-identical accumulation). LDS 25.6KB -> 6 blocks/CU.

template <int CH, bool HOUT>
__device__ __forceinline__ void gemm_att_tile48(const float* __restrict__ A,
                                                const float* __restrict__ B,
                                                void* __restrict__ Cv,
                                                const float* __restrict__ att_s,
                                                const float* __restrict__ att_d,
                                                float* __restrict__ a_s,
                                                float* __restrict__ a_d,
                                                int N, int K, int M,
                                                int row0, int col0, int tid,
                                                float (*As)[68], float (*Bs)[132]) {
    const int tx = tid & 15, ty = tid >> 4;
    float acc[4][8] = {};   // [row][col]: cols 0-3 = group0 (col0+tx*4), 4-7 = group1 (+64)

    for (int k0 = 0; k0 < K; k0 += 32) {
        {
            const int a_row = tid >> 2;          // 0..63
            const int a_k   = (tid & 3) * 8;     // 0,8,16,24
            const int gr    = row0 + a_row;
            float4 v0 = make_float4(0.f,0.f,0.f,0.f), v1 = make_float4(0.f,0.f,0.f,0.f);
            if (gr < N) {
                const float* ap = A + (size_t)gr * K + k0 + a_k;
                v0 = *(const float4*)ap;
                v1 = *(const float4*)(ap + 4);
            }
            As[a_k + 0][a_row] = v0.x; As[a_k + 1][a_row] = v0.y;
            As[a_k + 2][a_row] = v0.z; As[a_k + 3][a_row] = v0.w;
            As[a_k + 4][a_row] = v1.x; As[a_k + 5][a_row] = v1.y;
            As[a_k + 6][a_row] = v1.z; As[a_k + 7][a_row] = v1.w;
        }
        {
            const int b_k = tid >> 4;            // 0..15 (+16 second pass)
            const int b_c = (tid & 15) * 8;
            const float* bp0 = B + (size_t)(k0 + b_k) * M + col0 + b_c;
            const float* bp1 = B + (size_t)(k0 + b_k + 16) * M + col0 + b_c;
            *(float4*)&Bs[b_k][b_c]          = *(const float4*)bp0;
            *(float4*)&Bs[b_k][b_c + 4]      = *(const float4*)(bp0 + 4);
            *(float4*)&Bs[b_k + 16][b_c]     = *(const float4*)bp1;
            *(float4*)&Bs[b_k + 16][b_c + 4] = *(const float4*)(bp1 + 4);
        }
        __syncthreads();
        #pragma unroll
        for (int kk = 0; kk < 32; ++kk) {
            const float4 a  = *(const float4*)&As[kk][ty * 4];
            const float4 b0 = *(const float4*)&Bs[kk][tx * 4];        // group0
            const float4 b1 = *(const float4*)&Bs[kk][64 + tx * 4];   // group1
            const float av[4] = {a.x, a.y, a.z, a.w};
            const float bv[8] = {b0.x,b0.y,b0.z,b0.w,b1.x,b1.y,b1.z,b1.w};
            #pragma unroll
            for (int i = 0; i < 4; ++i)
                #pragma unroll
                for (int j = 0; j < 8; ++j)
                    acc[i][j] = fmaf(av[i], bv[j], acc[i][j]);
        }
        __syncthreads();
    }

    // epilogue: each thread holds 4 cols of TWO heads' column groups
    const int c0 = col0 + tx * 4;        // group0 cols
    const int c1 = c0 + 64;              // group1 cols
    const int head0 = c0 / CH, pos0 = c0 % CH;
    const int head1 = c1 / CH, pos1 = c1 % CH;
    float attS[8], attD[8];
    #pragma unroll
    for (int j = 0; j < 4; ++j) {
        attS[j]     = att_s[head0 * CH + pos0 + j];
        attD[j]     = att_d[head0 * CH + pos0 + j];
        attS[j + 4] = att_s[head1 * CH + pos1 + j];
        attD[j + 4] = att_d[head1 * CH + pos1 + j];
    }
    #pragma unroll
    for (int i = 0; i < 4; ++i) {
        const int r = row0 + ty * 4 + i;
        if (r < N) {
            if constexpr (HOUT) {
                __half* C = (__half*)Cv;
                __half* cp0 = C + (size_t)r * M + c0;
                __half* cp1 = C + (size_t)r * M + c1;
                *(__half2*)(cp0)     = __halves2half2(__float2half_rn(acc[i][0]), __float2half_rn(acc[i][1]));
                *(__half2*)(cp0 + 2) = __halves2half2(__float2half_rn(acc[i][2]), __float2half_rn(acc[i][3]));
                *(__half2*)(cp1)     = __halves2half2(__float2half_rn(acc[i][4]), __float2half_rn(acc[i][5]));
                *(__half2*)(cp1 + 2) = __halves2half2(__float2half_rn(acc[i][6]), __float2half_rn(acc[i][7]));
            } else {
                float* C = (float*)Cv;
                *(float4*)(C + (size_t)r * M + c0) = make_float4(acc[i][0], acc[i][1], acc[i][2], acc[i][3]);
                *(float4*)(C + (size_t)r * M + c1) = make_float4(acc[i][4], acc[i][5], acc[i][6], acc[i][7]);
            }
        }
        float ss0 = 0.f, sd0 = 0.f, ss1 = 0.f, sd1 = 0.f;
        #pragma unroll
        for (int j = 0; j < 4; ++j) {
            ss0 = fmaf(acc[i][j], attS[j], ss0);
            sd0 = fmaf(acc[i][j], attD[j], sd0);
            ss1 = fmaf(acc[i][j + 4], attS[j + 4], ss1);
            sd1 = fmaf(acc[i][j + 4], attD[j + 4], sd1);
        }
        #pragma unroll
        for (int msk = 1; msk < CH / 4; msk <<= 1) {
            ss0 += __shfl_xor(ss0, msk, 64);
            sd0 += __shfl_xor(sd0, msk, 64);
            ss1 += __shfl_xor(ss1, msk, 64);
            sd1 += __shfl_xor(sd1, msk, 64);
        }
        if ((tx & (CH / 4 - 1)) == 0 && r < N) {
            a_s[r * NH + head0] = ss0;
            a_d[r * NH + head0] = sd0;
            a_s[r * NH + head1] = ss1;
            a_d[r * NH + head1] = sd1;
        }
    }
}

__device__ __forceinline__ void gemm_pq_tile48(const float* __restrict__ A,
                                               const float* __restrict__ B,
                                               __half* __restrict__ C,
                                               int N, int K, int M,
                                               int row0, int col0, int tid,
                                               float (*As)[68], float (*Bs)[132]) {
    const int tx = tid & 15, ty = tid >> 4;
    float acc[4][8] = {};
    for (int k0 = 0; k0 < K; k0 += 32) {
        {
            const int a_row = tid >> 2;
            const int a_k   = (tid & 3) * 8;
            const int gr    = row0 + a_row;
            float4 v0 = make_float4(0.f,0.f,0.f,0.f), v1 = make_float4(0.f,0.f,0.f,0.f);
            if (gr < N) {
                const float* ap = A + (size_t)gr * K + k0 + a_k;
                v0 = *(const float4*)ap;
                v1 = *(const float4*)(ap + 4);
            }
            As[a_k + 0][a_row] = v0.x; As[a_k + 1][a_row] = v0.y;
            As[a_k + 2][a_row] = v0.z; As[a_k + 3][a_row] = v0.w;
            As[a_k + 4][a_row] = v1.x; As[a_k + 5][a_row] = v1.y;
            As[a_k + 6][a_row] = v1.z; As[a_k + 7][a_row] = v1.w;
        }
        {
            const int b_k = tid >> 4;
            const int b_c = (tid & 15) * 8;
            const float* bp0 = B + (size_t)(k0 + b_k) * M + col0 + b_c;
            const float* bp1 = B + (size_t)(k0 + b_k + 16) * M + col0 + b_c;
            *(float4*)&Bs[b_k][b_c]          = *(const float4*)bp0;
            *(float4*)&Bs[b_k][b_c + 4]      = *(const float4*)(bp0 + 4);
            *(float4*)&Bs[b_k + 16][b_c]     = *(const float4*)bp1;
            *(float4*)&Bs[b_k + 16][b_c + 4] = *(const float4*)(bp1 + 4);
        }
        __syncthreads();
        #pragma unroll
        for (int kk = 0; kk < 32; ++kk) {
            const float4 a  = *(const float4*)&As[kk][ty * 4];
            const float4 b0 = *(const float4*)&Bs[kk][tx * 4];
            const float4 b1 = *(const float4*)&Bs[kk][64 + tx * 4];
            const float av[4] = {a.x, a.y, a.z, a.w};
            const float bv[8] = {b0.x,b0.y,b0.z,b0.w,b1.x,b1.y,b1.z,b1.w};
            #pragma unroll
            for (int i = 0; i < 4; ++i)
                #pragma unroll
                for (int j = 0; j < 8; ++j)
                    acc[i][j] = fmaf(av[i], bv[j], acc[i][j]);
        }
        __syncthreads();
    }
    const int c0 = col0 + tx * 4;
    const int c1 = c0 + 64;
    #pragma unroll
    for (int i = 0; i < 4; ++i) {
        const int r = row0 + ty * 4 + i;
        if (r < N) {
            __half* cp0 = C + (size_t)r * M + c0;
            __half* cp1 = C + (size_t)r * M + c1;
            *(__half2*)(cp0)     = __halves2half2(__float2half_rn(acc[i][0]), __float2half_rn(acc[i][1]));
            *(__half2*)(cp0 + 2) = __halves2half2(__float2half_rn(acc[i][2]), __float2half_rn(acc[i][3]));
            *(__half2*)(cp1)     = __halves2half2(__float2half_rn(acc[i][4]), __float2half_rn(acc[i][5]));
            *(__half2*)(cp1 + 2) = __halves2half2(__float2half_rn(acc[i][6]), __float2half_rn(acc[i][7]));
        }
    }
}

// ================= softmax+aggregate device helpers (proven R4 bodies) =================

__device__ __forceinline__ void softagg1_node(int n, int lane,
                                              const int* __restrict__ rowptr,
                                              const int* __restrict__ psrc,
                                              const float* __restrict__ a_s,
                                              const float* __restrict__ a_d,
                                              const __half* __restrict__ xl,
                                              const float* __restrict__ bias,
                                              float* __restrict__ out) {
    const int r0 = rowptr[n], r1 = rowptr[n + 1];
    const int hh = lane >> 4;
    const float ad = a_d[n * NH + hh];

    const h4* X = (const h4*)xl;   // row stride 64 h4 units (256 halves)
    float4 A0 = {0,0,0,0}, A1 = {0,0,0,0}, A2 = {0,0,0,0}, A3 = {0,0,0,0};
    float sum = 0.f;
    int j = r0;
    for (; j + 7 < r1; j += 8) {
        const int s0 = psrc[j],     s1 = psrc[j + 1], s2 = psrc[j + 2], s3 = psrc[j + 3];
        const int s4 = psrc[j + 4], s5 = psrc[j + 5], s6 = psrc[j + 6], s7 = psrc[j + 7];
        const float w0 = elw(a_s[s0 * NH + hh] + ad);
        const float w1 = elw(a_s[s1 * NH + hh] + ad);
        const float w2 = elw(a_s[s2 * NH + hh] + ad);
        const float w3 = elw(a_s[s3 * NH + hh] + ad);
        const float w4 = elw(a_s[s4 * NH + hh] + ad);
        const float w5 = elw(a_s[s5 * NH + hh] + ad);
        const float w6 = elw(a_s[s6 * NH + hh] + ad);
        const float w7 = elw(a_s[s7 * NH + hh] + ad);
        sum += ((w0 + w1) + (w2 + w3)) + ((w4 + w5) + (w6 + w7));
        const h4 v0 = X[(size_t)s0 * 64 + lane];
        const h4 v1 = X[(size_t)s1 * 64 + lane];
        const h4 v2 = X[(size_t)s2 * 64 + lane];
        const h4 v3 = X[(size_t)s3 * 64 + lane];
        const h4 v4 = X[(size_t)s4 * 64 + lane];
        const h4 v5 = X[(size_t)s5 * 64 + lane];
        const h4 v6 = X[(size_t)s6 * 64 + lane];
        const h4 v7 = X[(size_t)s7 * 64 + lane];
        float2 l0 = __half22float2(v0.a), m0 = __half22float2(v0.b);
        float2 l1 = __half22float2(v1.a), m1 = __half22float2(v1.b);
        float2 l2 = __half22float2(v2.a), m2 = __half22float2(v2.b);
        float2 l3 = __half22float2(v3.a), m3 = __half22float2(v3.b);
        float2 l4 = __half22float2(v4.a), m4 = __half22float2(v4.b);
        float2 l5 = __half22float2(v5.a), m5 = __half22float2(v5.b);
        float2 l6 = __half22float2(v6.a), m6 = __half22float2(v6.b);
        float2 l7 = __half22float2(v7.a), m7 = __half22float2(v7.b);
        A0.x = fmaf(w0, l0.x, A0.x); A0.y = fmaf(w0, l0.y, A0.y);
        A0.z = fmaf(w0, m0.x, A0.z); A0.w = fmaf(w0, m0.y, A0.w);
        A1.x = fmaf(w1, l1.x, A1.x); A1.y = fmaf(w1, l1.y, A1.y);
        A1.z = fmaf(w1, m1.x, A1.z); A1.w = fmaf(w1, m1.y, A1.w);
        A2.x = fmaf(w2, l2.x, A2.x); A2.y = fmaf(w2, l2.y, A2.y);
        A2.z = fmaf(w2, m2.x, A2.z); A2.w = fmaf(w2, m2.y, A2.w);
        A3.x = fmaf(w3, l3.x, A3.x); A3.y = fmaf(w3, l3.y, A3.y);
        A3.z = fmaf(w3, m3.x, A3.z); A3.w = fmaf(w3, m3.y, A3.w);
        A0.x = fmaf(w4, l4.x, A0.x); A0.y = fmaf(w4, l4.y, A0.y);
        A0.z = fmaf(w4, m4.x, A0.z); A0.w = fmaf(w4, m4.y, A0.w);
        A1.x = fmaf(w5, l5.x, A1.x); A1.y = fmaf(w5, l5.y, A1.y);
        A1.z = fmaf(w5, m5.x, A1.z); A1.w = fmaf(w5, m5.y, A1.w);
        A2.x = fmaf(w6, l6.x, A2.x); A2.y = fmaf(w6, l6.y, A2.y);
        A2.z = fmaf(w6, m6.x, A2.z); A2.w = fmaf(w6, m6.y, A2.w);
        A3.x = fmaf(w7, l7.x, A3.x); A3.y = fmaf(w7, l7.y, A3.y);
        A3.z = fmaf(w7, m7.x, A3.z); A3.w = fmaf(w7, m7.y, A3.w);
    }
    for (; j < r1; ++j) {
        const int s0 = psrc[j];
        const float w0 = elw(a_s[s0 * NH + hh] + ad);
        sum += w0;
        const h4 v0 = X[(size_t)s0 * 64 + lane];
        float2 l0 = __half22float2(v0.a), m0 = __half22float2(v0.b);
        A0.x = fmaf(w0, l0.x, A0.x); A0.y = fmaf(w0, l0.y, A0.y);
        A0.z = fmaf(w0, m0.x, A0.z); A0.w = fmaf(w0, m0.y, A0.w);
    }
    const float inv = 1.f / (sum + 1e-30f);
    float4 t;
    t.x = ((A0.x + A1.x) + (A2.x + A3.x)) * inv;
    t.y = ((A0.y + A1.y) + (A2.y + A3.y)) * inv;
    t.z = ((A0.z + A1.z) + (A2.z + A3.z)) * inv;
    t.w = ((A0.w + A1.w) + (A2.w + A3.w)) * inv;
    #pragma unroll
    for (int msk = 16; msk < 64; msk <<= 1) {
        t.x += __shfl_xor(t.x, msk, 64);
        t.y += __shfl_xor(t.y, msk, 64);
        t.z += __shfl_xor(t.z, msk, 64);
        t.w += __shfl_xor(t.w, msk, 64);
    }
    if (lane < 16) {
        const float4 b = ((const float4*)bias)[lane];
        float4 o;
        o.x = t.x * 0.25f + b.x; o.y = t.y * 0.25f + b.y;
        o.z = t.z * 0.25f + b.z; o.w = t.w * 0.25f + b.w;
        ((float4*)out)[(size_t)n * 16 + lane] = o;
    }
}

__device__ __forceinline__ void softagg2_node(int n, int lane,
                                              const int* __restrict__ rowptr,
                                              const int* __restrict__ psrc,
                                              const float* __restrict__ a_s,
                                              const float* __restrict__ a_d,
                                              float* __restrict__ alpha_p,
                                              float* __restrict__ inv_s,
                                              const __half* __restrict__ xl,
                                              const float* __restrict__ bias,
                                              float* __restrict__ out) {
    const int r0 = rowptr[n], r1 = rowptr[n + 1];
    const int cl = lane & 31, half = lane >> 5, hh = cl >> 3;
    const float ad = a_d[n * NH + hh];
    const bool writer = (cl & 7) == 0;   // one lane per (half, head) writes raw w

    const h4* X = (const h4*)xl;   // row stride 32 h4 units (128 halves)
    float4 A0 = {0,0,0,0}, A1 = {0,0,0,0};
    float sum = 0.f;
    int j = r0;
    for (; j + 7 < r1; j += 8) {
        const int ja = j + half, jc = j + 2 + half, je = j + 4 + half, jg = j + 6 + half;
        const int sa = psrc[ja], sc = psrc[jc], se = psrc[je], sg = psrc[jg];
        const float wa = elw(a_s[sa * NH + hh] + ad);
        const float wc = elw(a_s[sc * NH + hh] + ad);
        const float we = elw(a_s[se * NH + hh] + ad);
        const float wg = elw(a_s[sg * NH + hh] + ad);
        if (writer) {
            alpha_p[ja * NH + hh] = wa; alpha_p[jc * NH + hh] = wc;
            alpha_p[je * NH + hh] = we; alpha_p[jg * NH + hh] = wg;
        }
        sum += (wa + wc) + (we + wg);
        const h4 va = X[(size_t)sa * 32 + cl];
        const h4 vc = X[(size_t)sc * 32 + cl];
        const h4 ve = X[(size_t)se * 32 + cl];
        const h4 vg = X[(size_t)sg * 32 + cl];
        const float2 la = __half22float2(va.a), ma = __half22float2(va.b);
        const float2 lc = __half22float2(vc.a), mc = __half22float2(vc.b);
        const float2 le = __half22float2(ve.a), me = __half22float2(ve.b);
        const float2 lg = __half22float2(vg.a), mg = __half22float2(vg.b);
        A0.x = fmaf(wa, la.x, A0.x); A0.y = fmaf(wa, la.y, A0.y);
        A0.z = fmaf(wa, ma.x, A0.z); A0.w = fmaf(wa, ma.y, A0.w);
        A1.x = fmaf(wc, lc.x, A1.x); A1.y = fmaf(wc, lc.y, A1.y);
        A1.z = fmaf(wc, mc.x, A1.z); A1.w = fmaf(wc, mc.y, A1.w);
        A0.x = fmaf(we, le.x, A0.x); A0.y = fmaf(we, le.y, A0.y);
        A0.z = fmaf(we, me.x, A0.z); A0.w = fmaf(we, me.y, A0.w);
        A1.x = fmaf(wg, lg.x, A1.x); A1.y = fmaf(wg, lg.y, A1.y);
        A1.z = fmaf(wg, mg.x, A1.z); A1.w = fmaf(wg, mg.y, A1.w);
    }
    for (; j < r1; j += 2) {
        const int ja = j + half;
        const bool valid = ja < r1;
        const int sa = psrc[valid ? ja : r0];
        float wa = 0.f;
        if (valid) {
            wa = elw(a_s[sa * NH + hh] + ad);
            if (writer) alpha_p[ja * NH + hh] = wa;
        }
        sum += wa;
        const h4 va = X[(size_t)sa * 32 + cl];
        const float2 la = __half22float2(va.a), ma = __half22float2(va.b);
        A0.x = fmaf(wa, la.x, A0.x); A0.y = fmaf(wa, la.y, A0.y);
        A0.z = fmaf(wa, ma.x, A0.z); A0.w = fmaf(wa, ma.y, A0.w);
    }
    // merge halves' partial sums, then normalize
    sum += __shfl_xor(sum, 32, 64);
    const float inv = 1.f / (sum + 1e-30f);
    if (writer && half == 0) inv_s[n * NH + hh] = inv;

    float4 t;
    t.x = A0.x + A1.x; t.y = A0.y + A1.y; t.z = A0.z + A1.z; t.w = A0.w + A1.w;
    t.x += __shfl_xor(t.x, 32, 64);
    t.y += __shfl_xor(t.y, 32, 64);
    t.z += __shfl_xor(t.z, 32, 64);
    t.w += __shfl_xor(t.w, 32, 64);
    t.x *= inv; t.y *= inv; t.z *= inv; t.w *= inv;
    #pragma unroll
    for (int q = 0; q < 2; ++q) {
        const int msk = (q == 0) ? 8 : 16;
        t.x += __shfl_xor(t.x, msk, 64);
        t.y += __shfl_xor(t.y, msk, 64);
        t.z += __shfl_xor(t.z, msk, 64);
        t.w += __shfl_xor(t.w, msk, 64);
    }
    if (lane < 8) {
        const float4 b = ((const float4*)bias)[lane];
        float4 o;
        o.x = t.x * 0.25f + b.x; o.y = t.y * 0.25f + b.y;
        o.z = t.z * 0.25f + b.z; o.w = t.w * 0.25f + b.w;
        ((float4*)out)[(size_t)n * 8 + lane] = o;
    }
}

// ================= kernels =================

__global__ __launch_bounds__(256) void count_deg_k(const int* __restrict__ ei,
                                                   int* __restrict__ deg) {
    const int e = blockIdx.x * 256 + threadIdx.x;
    if (e < EE) atomicAdd(&deg[ei[EE + e]], 1);
}

__global__ __launch_bounds__(256) void pack_w1_k(const float* __restrict__ mW1,
                                                 float* __restrict__ W1pq) {
    const int idx = blockIdx.x * 256 + threadIdx.x;
    if (idx >= 32 * 128) return;
    const int k = idx >> 7, j = idx & 127;
    W1pq[idx] = (j < 64) ? mW1[k * 64 + j] : mW1[(36 + k) * 64 + (j - 64)];
}

template <int CH, bool HOUT>
__global__ __launch_bounds__(256) void gemm_att48_k(const float* __restrict__ A,
                                                    const float* __restrict__ B,
                                                    void* __restrict__ Cv,
                                                    const float* __restrict__ att_s,
                                                    const float* __restrict__ att_d,
                                                    float* __restrict__ a_s,
                                                    float* __restrict__ a_d,
                                                    int N, int K, int M) {
    __shared__ float As[32][68];
    __shared__ float Bs[32][132];
    gemm_att_tile48<CH, HOUT>(A, B, Cv, att_s, att_d, a_s, a_d, N, K, M,
                              blockIdx.x * 64, blockIdx.y * 128, threadIdx.x, As, Bs);
}

__global__ __launch_bounds__(256) void gemm_pq48_k(const float* __restrict__ A,
                                                   const float* __restrict__ B,
                                                   __half* __restrict__ C,
                                                   int N, int K, int M) {
    __shared__ float As[32][68];
    __shared__ float Bs[32][132];
    gemm_pq_tile48(A, B, C, N, K, M, blockIdx.x * 64, blockIdx.y * 128, threadIdx.x, As, Bs);
}

// ---- multi-block exclusive scan (3 phases; HW-verified logic) ----
__global__ __launch_bounds__(256) void scan1_k(const int* __restrict__ deg,
                                               int* __restrict__ bsum) {
    __shared__ int sw[4];
    const int tid = threadIdx.x, lane = tid & 63, wv = tid >> 6;
    const int i = blockIdx.x * 256 + tid;
    int s = (i < NN) ? deg[i] : 0;
    #pragma unroll
    for (int d = 1; d < 64; d <<= 1) s += __shfl_xor(s, d, 64);
    if (lane == 0) sw[wv] = s;
    __syncthreads();
    if (tid == 0) bsum[blockIdx.x] = sw[0] + sw[1] + sw[2] + sw[3];
}

__global__ __launch_bounds__(256) void scan2_k(const int* __restrict__ bsum,
                                               int* __restrict__ boff) {
    __shared__ int sw[8];
    const int tid = threadIdx.x, lane = tid & 63, wv = tid >> 6;
    int v = (tid < NCH) ? bsum[tid] : 0;
    int incl = v;
    #pragma unroll
    for (int d = 1; d < 64; d <<= 1) {
        int t = __shfl_up(incl, d, 64);
        if (lane >= d) incl += t;
    }
    if (lane == 63) sw[wv] = incl;
    __syncthreads();
    if (wv == 0 && lane < 4) {
        int s4 = sw[lane];
        #pragma unroll
        for (int d = 1; d < 4; d <<= 1) {
            int t = __shfl_up(s4, d, 64);
            if (lane >= d) s4 += t;
        }
        sw[lane + 4] = s4;
    }
    __syncthreads();
    const int woff = (wv > 0) ? sw[wv - 1 + 4] : 0;
    if (tid < NCH) boff[tid] = woff + incl - v;
}

__global__ __launch_bounds__(256) void scan3_k(const int* __restrict__ deg,
                                               const int* __restrict__ boff,
                                               int* __restrict__ rowptr,
                                               int* __restrict__ cursor) {
    __shared__ int sw[8];
    const int tid = threadIdx.x, lane = tid & 63, wv = tid >> 6;
    const int c = blockIdx.x;
    const int i = c * 256 + tid;
    int v = (i < NN) ? deg[i] : 0;
    int incl = v;
    #pragma unroll
    for (int d = 1; d < 64; d <<= 1) {
        int t = __shfl_up(incl, d, 64);
        if (lane >= d) incl += t;
    }
    if (lane == 63) sw[wv] = incl;
    __syncthreads();
    if (wv == 0 && lane < 4) {
        int s4 = sw[lane];
        #pragma unroll
        for (int d = 1; d < 4; d <<= 1) {
            int t = __shfl_up(s4, d, 64);
            if (lane >= d) s4 += t;
        }
        sw[lane + 4] = s4;
    }
    __syncthreads();
    const int excl = boff[c] + ((wv > 0) ? sw[wv - 1 + 4] : 0) + incl - v;
    if (i < NN) { rowptr[i] = excl; cursor[i] = excl; }
    if (c == 0 && tid == 0) rowptr[NN] = EE;
}

__global__ __launch_bounds__(256) void scatter_perm_k(const int* __restrict__ ei,
                                                      int* __restrict__ cursor,
                                                      int* __restrict__ perm,
                                                      int* __restrict__ psrc,
                                                      int* __restrict__ pdst) {
    const int e = blockIdx.x * 256 + threadIdx.x;
    if (e >= EE) return;
    const int d = ei[EE + e];
    const int p = atomicAdd(&cursor[d], 1);
    perm[p] = e;
    psrc[p] = ei[e];
    pdst[p] = d;
}

__global__ __launch_bounds__(256) void softagg1h_k(const int* __restrict__ rowptr,
                                                   const int* __restrict__ psrc,
                                                   const float* __restrict__ a_s,
                                                   const float* __restrict__ a_d,
                                                   const __half* __restrict__ xl,
                                                   const float* __restrict__ bias,
                                                   float* __restrict__ out) {
    const int n = blockIdx.x * 4 + (threadIdx.x >> 6);
    if (n >= NN) return;
    softagg1_node(n, threadIdx.x & 63, rowptr, psrc, a_s, a_d, xl, bias, out);
}

__global__ __launch_bounds__(256) void softagg2h_k(const int* __restrict__ rowptr,
                                                   const int* __restrict__ psrc,
                                                   const float* __restrict__ a_s,
                                                   const float* __restrict__ a_d,
                                                   float* __restrict__ alpha_p,
                                                   float* __restrict__ inv_s,
                                                   const __half* __restrict__ xl,
                                                   const float* __restrict__ bias,
                                                   float* __restrict__ out) {
    const int n = blockIdx.x * 4 + (threadIdx.x >> 6);
    if (n >= NN) return;
    softagg2_node(n, threadIdx.x & 63, rowptr, psrc, a_s, a_d, alpha_p, inv_s, xl, bias, out);
}

__global__ __launch_bounds__(256) void edge_mlp_k(const __half* __restrict__ PQ,
                                                  const float* __restrict__ alpha_p,
                                                  const float* __restrict__ inv_s,
                                                  const int* __restrict__ psrc,
                                                  const int* __restrict__ pdst,
                                                  const int* __restrict__ perm,
                                                  const float* __restrict__ mW1,
                                                  const float* __restrict__ mb1,
                                                  const float* __restrict__ mW2,
                                                  const float* __restrict__ mb2,
                                                  float* __restrict__ out) {
    const int lane = threadIdx.x & 63, wvv = threadIdx.x >> 6;
    const int g = lane >> 4, c = lane & 15;

    const float4 wa0 = *(const float4*)&mW1[32 * 64 + c * 4];
    const float4 wa1 = *(const float4*)&mW1[33 * 64 + c * 4];
    const float4 wa2 = *(const float4*)&mW1[34 * 64 + c * 4];
    const float4 wa3 = *(const float4*)&mW1[35 * 64 + c * 4];
    const float4 b1v = *(const float4*)&mb1[c * 4];
    const float4 w2a = *(const float4*)&mW2[c * 8];
    const float4 w2b = *(const float4*)&mW2[c * 8 + 4];
    const float bo0 = mb2[0], bo1 = mb2[1];

    const h4* PQ4 = (const h4*)PQ;
    const int gw = blockIdx.x * 4 + wvv;
    const int stride4 = gridDim.x * 4 * 4;

    for (int jb = gw * 4; jb < EE; jb += stride4) {
        const int j = jb + g;
        const int s = psrc[j];
        const int d = pdst[j];
        const float4 ar = *(const float4*)&alpha_p[(size_t)j * 4];
        const float4 iv = *(const float4*)&inv_s[(size_t)d * 4];
        const float al0 = ar.x * iv.x, al1 = ar.y * iv.y;
        const float al2 = ar.z * iv.z, al3 = ar.w * iv.w;
        const h4 ph = PQ4[(size_t)s * 32 + c];
        const h4 qh = PQ4[(size_t)d * 32 + 16 + c];
        const float2 pl = __half22float2(ph.a), pm = __half22float2(ph.b);
        const float2 ql = __half22float2(qh.a), qm = __half22float2(qh.b);
        float4 h;
        h.x = pl.x + ql.x + b1v.x; h.y = pl.y + ql.y + b1v.y;
        h.z = pm.x + qm.x + b1v.z; h.w = pm.y + qm.y + b1v.w;
        h.x = fmaf(al0, wa0.x, h.x); h.y = fmaf(al0, wa0.y, h.y);
        h.z = fmaf(al0, wa0.z, h.z); h.w = fmaf(al0, wa0.w, h.w);
        h.x = fmaf(al1, wa1.x, h.x); h.y = fmaf(al1, wa1.y, h.y);
        h.z = fmaf(al1, wa1.z, h.z); h.w = fmaf(al1, wa1.w, h.w);
        h.x = fmaf(al2, wa2.x, h.x); h.y = fmaf(al2, wa2.y, h.y);
        h.z = fmaf(al2, wa2.z, h.z); h.w = fmaf(al2, wa2.w, h.w);
        h.x = fmaf(al3, wa3.x, h.x); h.y = fmaf(al3, wa3.y, h.y);
        h.z = fmaf(al3, wa3.z, h.z); h.w = fmaf(al3, wa3.w, h.w);
        h.x = fmaxf(h.x, 0.f); h.y = fmaxf(h.y, 0.f);
        h.z = fmaxf(h.z, 0.f); h.w = fmaxf(h.w, 0.f);

        float v0 = h.x * w2a.x + h.y * w2a.z + h.z * w2b.x + h.w * w2b.z;
        float v1 = h.x * w2a.y + h.y * w2a.w + h.z * w2b.y + h.w * w2b.w;
        #pragma unroll
        for (int msk = 1; msk < 16; msk <<= 1) {
            v0 += __shfl_xor(v0, msk, 64);
            v1 += __shfl_xor(v1, msk, 64);
        }
        if (c == 0)
            *(float2*)&out[(size_t)perm[j] * 2] = make_float2(v0 + bo0, v1 + bo1);
    }
}

extern "C" void kernel_launch(void* const* d_in, const int* in_sizes, int n_in,
                              void* d_out, int out_size, void* d_ws, size_t ws_size,
                              hipStream_t stream) {
    const float* x        = (const float*)d_in[0];
    const int*   ei       = (const int*)d_in[1];
    // d_in[2] edge_attr: unused (edge_dim=None). d_in[3] flag: unused.
    const float* W1       = (const float*)d_in[4];
    const float* att1_src = (const float*)d_in[5];
    const float* att1_dst = (const float*)d_in[6];
    const float* b1       = (const float*)d_in[7];
    const float* W3       = (const float*)d_in[8];
    const float* att3_src = (const float*)d_in[9];
    const float* att3_dst = (const float*)d_in[10];
    const float* b3       = (const float*)d_in[11];
    const float* mW1      = (const float*)d_in[12];
    const float* mb1      = (const float*)d_in[13];
    const float* mW2      = (const float*)d_in[14];
    const float* mb2      = (const float*)d_in[15];

    float* out_nodes = (float*)d_out;               // [N,32]
    float* out_edges = out_nodes + (size_t)NN * 32; // [E,2]

    // workspace layout (floats/ints)
    float* ws = (float*)d_ws;
    __half*   xlh     = (__half*)ws;                  // N*256 halves (layer-1 GEMM out)
    __half*   xl2h    = (__half*)ws;                  // N*128 halves (layer-2 GEMM out)
    __half*   PQh     = (__half*)ws;                  // N*128 halves, after xl2h dead
    float*    h1      = ws + 12800000;                // N*64
    float*    alpha_p = ws + 16000000;                // E*4 (CSR-order raw w, layer 2)
    float*    a_s     = ws + 25600000;                // N*4
    float*    a_d     = ws + 25800000;                // N*4
    float*    W1pq    = ws + 26000000;                // 32*128
    float*    inv_s   = ws + 26100000;                // N*4
    int*      bsum    = (int*)(ws + 26300000);        // NCH
    int*      boff    = (int*)(ws + 26301000);        // NCH
    int*      deg     = (int*)(ws + 26400000);        // N
    int*      cursor  = (int*)(ws + 26450000);        // N
    int*      rowptr  = (int*)(ws + 26500000);        // N+1
    int*      perm    = (int*)(ws + 26550008);        // E
    int*      psrc    = (int*)(ws + 27350008);        // E
    int*      pdst    = (int*)(ws + 28150008);        // E

    const int NB4 = (NN + 3) / 4;

    // 1) CSR build front half (de-fused for attribution; boundaries ~1.5us each)
    hipMemsetAsync(deg, 0, (size_t)NN * 4, stream);
    count_deg_k<<<EB, 256, 0, stream>>>(ei, deg);
    pack_w1_k<<<16, 256, 0, stream>>>(mW1, W1pq);
    // 2) layer-1 GEMM (64x128 tile, BK=32 -> 8 barriers total)
    gemm_att48_k<64, true><<<dim3(GR64, 2), 256, 0, stream>>>(x, W1, xlh,
                                                              att1_src, att1_dst,
                                                              a_s, a_d, NN, INF, NH * 64);
    // 3) multi-block exclusive scan -> rowptr/cursor
    scan1_k<<<NCH, 256, 0, stream>>>(deg, bsum);
    scan2_k<<<1, 256, 0, stream>>>(bsum, boff);
    scan3_k<<<NCH, 256, 0, stream>>>(deg, boff, rowptr, cursor);
    // 4) scatter edges into CSR order
    scatter_perm_k<<<EB, 256, 0, stream>>>(ei, cursor, perm, psrc, pdst);
    // 5) layer-1 softmax+aggregate
    softagg1h_k<<<NB4, 256, 0, stream>>>(rowptr, psrc, a_s, a_d, xlh, b1, h1);
    // 6) layer-2 GEMM (K=64 -> 2 K-steps, 4 barriers)
    gemm_att48_k<32, true><<<dim3(GR64, 1), 256, 0, stream>>>(h1, W3, xl2h,
                                                              att3_src, att3_dst,
                                                              a_s, a_d, NN, 64, NH * 32);
    // 7) layer-2 softmax+aggregate
    softagg2h_k<<<NB4, 256, 0, stream>>>(rowptr, psrc, a_s, a_d, alpha_p, inv_s, xl2h, b3,
                                         out_nodes);
    // 8) PQ GEMM (K=32 -> single K-step; xl2h dead -> PQh aliases it)
    gemm_pq48_k<<<dim3(GR64, 1), 256, 0, stream>>>(out_nodes, W1pq, PQh, NN, 32, 128);
    // 9) edge MLP
    edge_mlp_k<<<2048, 256, 0, stream>>>(PQh, alpha_p, inv_s, psrc, pdst, perm,
                                         mW1, mb1, mW2, mb2, out_edges);
}

// Round 10
// 426.860 us; speedup vs baseline: 1.0542x; 1.0542x over previous
//
#include <hip/hip_runtime.h>
#include <hip/hip_fp16.h>

// Problem constants
constexpr int NN   = 50000;
constexpr int EE   = 800000;
constexpr int INF  = 128;   // input feat
constexpr int NH   = 4;     // heads
constexpr int GR64 = (NN + 63) / 64;        // 782 row tiles
constexpr int EB   = (EE + 255) / 256;      // 3125 edge blocks
constexpr int NCH  = (NN + 255) / 256;      // 196 scan chunks

struct __align__(8) h4 { __half2 a, b; };   // 4 halves = 8 bytes

typedef short bf16x8 __attribute__((ext_vector_type(8)));
typedef float f32x4v __attribute__((ext_vector_type(4)));

__device__ __forceinline__ float elw(float a) {
    a = (a > 0.f) ? a : 0.2f * a;          // leaky_relu(0.2)
    return __expf(a);                       // exp without max-sub (scores bounded)
}

__device__ __forceinline__ short bf16_hi(float x) {
    return (short)(__float_as_uint(x) >> 16);   // truncate to bf16
}
__device__ __forceinline__ float bf16_back(short h) {
    return __uint_as_float(((unsigned)(unsigned short)h) << 16);
}

// ======== Layer-1 GEMM on MATRIX CORES: split-bf16 (hi+lo), fp32-grade accuracy ========
// C = x@W1 [N,128]x[128,256]. Per block: 64 rows x 64 cols (= one head), K-loop 2x64.
// x = xh + xl (bf16 trunc, residual exact); C ~= xh*wh + xl*wh + xh*wl (lo*lo ~2^-16, dropped).
// 3 mfma_f32_16x16x32_bf16 per (cf,kf) into one fp32 acc. C/D layout (HW-verified):
// col = lane&15, row = (lane>>4)*4 + reg. A: row=lane&15, k=(lane>>4)*8+j; B: col=lane&15, same k.
__global__ __launch_bounds__(256) void gemm1_mfma_k(const float* __restrict__ A,   // x [N][128]
                                                    const float* __restrict__ B,   // W1 [128][256]
                                                    __half* __restrict__ C,        // xlh [N][256]
                                                    const float* __restrict__ att_s,
                                                    const float* __restrict__ att_d,
                                                    float* __restrict__ a_s,
                                                    float* __restrict__ a_d) {
    // [64][72] bf16: row stride 144B (16B-aligned for b128; bank shift 4 -> 2-way = free)
    __shared__ short Ah[64][72], Al[64][72];
    __shared__ short Bh[64][72], Bl[64][72];   // transposed: [col][k_local]
    const int tid  = threadIdx.x;
    const int lane = tid & 63, w = tid >> 6;
    const int row0 = blockIdx.x * 64;
    const int head = blockIdx.y;              // 64 cols per head
    const int c0   = head * 64;

    const int rl = lane & 15, gq = lane >> 4;

    f32x4v acc0 = {0,0,0,0}, acc1 = {0,0,0,0}, acc2 = {0,0,0,0}, acc3 = {0,0,0,0};

    for (int ks = 0; ks < 2; ++ks) {
        // ---- stage A (64 rows x 64 k), split hi/lo ----
        {
            const int ar = tid >> 2;               // 0..63
            const int kb = (tid & 3) * 4;          // 0,4,8,12
            const int grow = row0 + ar;
            #pragma unroll
            for (int pass = 0; pass < 4; ++pass) {
                const int kl = kb + pass * 16;     // 0..63
                float4 v = make_float4(0.f, 0.f, 0.f, 0.f);
                if (grow < NN) v = *(const float4*)(A + (size_t)grow * 128 + ks * 64 + kl);
                short4 hi, lo;
                hi.x = bf16_hi(v.x); lo.x = bf16_hi(v.x - bf16_back(hi.x));
                hi.y = bf16_hi(v.y); lo.y = bf16_hi(v.y - bf16_back(hi.y));
                hi.z = bf16_hi(v.z); lo.z = bf16_hi(v.z - bf16_back(hi.z));
                hi.w = bf16_hi(v.w); lo.w = bf16_hi(v.w - bf16_back(hi.w));
                *(short4*)&Ah[ar][kl] = hi;
                *(short4*)&Al[ar][kl] = lo;
            }
        }
        // ---- stage B transposed (64 k x 64 cols -> Bt[col][k]), split hi/lo ----
        {
            const int c  = lane;                   // 0..63
            const int kb = w * 16;                 // 16 k per wave
            #pragma unroll
            for (int chunk = 0; chunk < 2; ++chunk) {
                short hi8[8], lo8[8];
                #pragma unroll
                for (int i = 0; i < 8; ++i) {
                    const int kl = kb + chunk * 8 + i;
                    const float v = B[(size_t)(ks * 64 + kl) * 256 + c0 + c];
                    hi8[i] = bf16_hi(v);
                    lo8[i] = bf16_hi(v - bf16_back(hi8[i]));
                }
                *(bf16x8*)&Bh[c][kb + chunk * 8] =
                    (bf16x8){hi8[0],hi8[1],hi8[2],hi8[3],hi8[4],hi8[5],hi8[6],hi8[7]};
                *(bf16x8*)&Bl[c][kb + chunk * 8] =
                    (bf16x8){lo8[0],lo8[1],lo8[2],lo8[3],lo8[4],lo8[5],lo8[6],lo8[7]};
            }
        }
        __syncthreads();

        // ---- A-frags for this wave's 16 rows ----
        bf16x8 aH0 = *(const bf16x8*)&Ah[w * 16 + rl][gq * 8];
        bf16x8 aH1 = *(const bf16x8*)&Ah[w * 16 + rl][32 + gq * 8];
        bf16x8 aL0 = *(const bf16x8*)&Al[w * 16 + rl][gq * 8];
        bf16x8 aL1 = *(const bf16x8*)&Al[w * 16 + rl][32 + gq * 8];

        #pragma unroll
        for (int cf = 0; cf < 4; ++cf) {
            const int bc = cf * 16 + rl;
            bf16x8 bH0 = *(const bf16x8*)&Bh[bc][gq * 8];
            bf16x8 bH1 = *(const bf16x8*)&Bh[bc][32 + gq * 8];
            bf16x8 bL0 = *(const bf16x8*)&Bl[bc][gq * 8];
            bf16x8 bL1 = *(const bf16x8*)&Bl[bc][32 + gq * 8];
            f32x4v t = (cf == 0) ? acc0 : (cf == 1) ? acc1 : (cf == 2) ? acc2 : acc3;
            t = __builtin_amdgcn_mfma_f32_16x16x32_bf16(aH0, bH0, t, 0, 0, 0);
            t = __builtin_amdgcn_mfma_f32_16x16x32_bf16(aL0, bH0, t, 0, 0, 0);
            t = __builtin_amdgcn_mfma_f32_16x16x32_bf16(aH0, bL0, t, 0, 0, 0);
            t = __builtin_amdgcn_mfma_f32_16x16x32_bf16(aH1, bH1, t, 0, 0, 0);
            t = __builtin_amdgcn_mfma_f32_16x16x32_bf16(aL1, bH1, t, 0, 0, 0);
            t = __builtin_amdgcn_mfma_f32_16x16x32_bf16(aH1, bL1, t, 0, 0, 0);
            if (cf == 0) acc0 = t; else if (cf == 1) acc1 = t;
            else if (cf == 2) acc2 = t; else acc3 = t;
        }
        __syncthreads();
    }

    // ---- epilogue: store fp16 C + fused attention scores (block = one head) ----
    float sS[4] = {0.f, 0.f, 0.f, 0.f};
    float sD[4] = {0.f, 0.f, 0.f, 0.f};
    #pragma unroll
    for (int cf = 0; cf < 4; ++cf) {
        const f32x4v t = (cf == 0) ? acc0 : (cf == 1) ? acc1 : (cf == 2) ? acc2 : acc3;
        const int gcol = c0 + cf * 16 + rl;
        const float atS = att_s[gcol];      // att layout [4][64] -> flat index = gcol
        const float atD = att_d[gcol];
        #pragma unroll
        for (int r = 0; r < 4; ++r) {
            const int grow = row0 + w * 16 + gq * 4 + r;
            if (grow < NN) C[(size_t)grow * 256 + gcol] = __float2half_rn(t[r]);
            sS[r] = fmaf(t[r], atS, sS[r]);
            sD[r] = fmaf(t[r], atD, sD[r]);
        }
    }
    #pragma unroll
    for (int r = 0; r < 4; ++r) {
        #pragma unroll
        for (int msk = 1; msk < 16; msk <<= 1) {
            sS[r] += __shfl_xor(sS[r], msk, 64);
            sD[r] += __shfl_xor(sD[r], msk, 64);
        }
    }
    if (rl == 0) {
        #pragma unroll
        for (int r = 0; r < 4; ++r) {
            const int grow = row0 + w * 16 + gq * 4 + r;
            if (grow < NN) {
                a_s[grow * NH + head] = sS[r];
                a_d[grow * NH + head] = sD[r];
            }
        }
    }
}

// ======== 64x128 tile fp32 GEMM, BK=32 (kept for layer-2 / PQ) ========
template <int CH, bool HOUT>
__device__ __forceinline__ void gemm_att_tile48(const float* __restrict__ A,
                                                const float* __restrict__ B,
                                                void* __restrict__ Cv,
                                                const float* __restrict__ att_s,
                                                const float* __restrict__ att_d,
                                                float* __restrict__ a_s,
                                                float* __restrict__ a_d,
                                                int N, int K, int M,
                                                int row0, int col0, int tid,
                                                float (*As)[68], float (*Bs)[132]) {
    const int tx = tid & 15, ty = tid >> 4;
    float acc[4][8] = {};

    for (int k0 = 0; k0 < K; k0 += 32) {
        {
            const int a_row = tid >> 2;
            const int a_k   = (tid & 3) * 8;
            const int gr    = row0 + a_row;
            float4 v0 = make_float4(0.f,0.f,0.f,0.f), v1 = make_float4(0.f,0.f,0.f,0.f);
            if (gr < N) {
                const float* ap = A + (size_t)gr * K + k0 + a_k;
                v0 = *(const float4*)ap;
                v1 = *(const float4*)(ap + 4);
            }
            As[a_k + 0][a_row] = v0.x; As[a_k + 1][a_row] = v0.y;
            As[a_k + 2][a_row] = v0.z; As[a_k + 3][a_row] = v0.w;
            As[a_k + 4][a_row] = v1.x; As[a_k + 5][a_row] = v1.y;
            As[a_k + 6][a_row] = v1.z; As[a_k + 7][a_row] = v1.w;
        }
        {
            const int b_k = tid >> 4;
            const int b_c = (tid & 15) * 8;
            const float* bp0 = B + (size_t)(k0 + b_k) * M + col0 + b_c;
            const float* bp1 = B + (size_t)(k0 + b_k + 16) * M + col0 + b_c;
            *(float4*)&Bs[b_k][b_c]          = *(const float4*)bp0;
            *(float4*)&Bs[b_k][b_c + 4]      = *(const float4*)(bp0 + 4);
            *(float4*)&Bs[b_k + 16][b_c]     = *(const float4*)bp1;
            *(float4*)&Bs[b_k + 16][b_c + 4] = *(const float4*)(bp1 + 4);
        }
        __syncthreads();
        #pragma unroll
        for (int kk = 0; kk < 32; ++kk) {
            const float4 a  = *(const float4*)&As[kk][ty * 4];
            const float4 b0 = *(const float4*)&Bs[kk][tx * 4];
            const float4 b1 = *(const float4*)&Bs[kk][64 + tx * 4];
            const float av[4] = {a.x, a.y, a.z, a.w};
            const float bv[8] = {b0.x,b0.y,b0.z,b0.w,b1.x,b1.y,b1.z,b1.w};
            #pragma unroll
            for (int i = 0; i < 4; ++i)
                #pragma unroll
                for (int j = 0; j < 8; ++j)
                    acc[i][j] = fmaf(av[i], bv[j], acc[i][j]);
        }
        __syncthreads();
    }

    const int c0 = col0 + tx * 4;
    const int c1 = c0 + 64;
    const int head0 = c0 / CH, pos0 = c0 % CH;
    const int head1 = c1 / CH, pos1 = c1 % CH;
    float attS[8], attD[8];
    #pragma unroll
    for (int j = 0; j < 4; ++j) {
        attS[j]     = att_s[head0 * CH + pos0 + j];
        attD[j]     = att_d[head0 * CH + pos0 + j];
        attS[j + 4] = att_s[head1 * CH + pos1 + j];
        attD[j + 4] = att_d[head1 * CH + pos1 + j];
    }
    #pragma unroll
    for (int i = 0; i < 4; ++i) {
        const int r = row0 + ty * 4 + i;
        if (r < N) {
            if constexpr (HOUT) {
                __half* C = (__half*)Cv;
                __half* cp0 = C + (size_t)r * M + c0;
                __half* cp1 = C + (size_t)r * M + c1;
                *(__half2*)(cp0)     = __halves2half2(__float2half_rn(acc[i][0]), __float2half_rn(acc[i][1]));
                *(__half2*)(cp0 + 2) = __halves2half2(__float2half_rn(acc[i][2]), __float2half_rn(acc[i][3]));
                *(__half2*)(cp1)     = __halves2half2(__float2half_rn(acc[i][4]), __float2half_rn(acc[i][5]));
                *(__half2*)(cp1 + 2) = __halves2half2(__float2half_rn(acc[i][6]), __float2half_rn(acc[i][7]));
            } else {
                float* C = (float*)Cv;
                *(float4*)(C + (size_t)r * M + c0) = make_float4(acc[i][0], acc[i][1], acc[i][2], acc[i][3]);
                *(float4*)(C + (size_t)r * M + c1) = make_float4(acc[i][4], acc[i][5], acc[i][6], acc[i][7]);
            }
        }
        float ss0 = 0.f, sd0 = 0.f, ss1 = 0.f, sd1 = 0.f;
        #pragma unroll
        for (int j = 0; j < 4; ++j) {
            ss0 = fmaf(acc[i][j], attS[j], ss0);
            sd0 = fmaf(acc[i][j], attD[j], sd0);
            ss1 = fmaf(acc[i][j + 4], attS[j + 4], ss1);
            sd1 = fmaf(acc[i][j + 4], attD[j + 4], sd1);
        }
        #pragma unroll
        for (int msk = 1; msk < CH / 4; msk <<= 1) {
            ss0 += __shfl_xor(ss0, msk, 64);
            sd0 += __shfl_xor(sd0, msk, 64);
            ss1 += __shfl_xor(ss1, msk, 64);
            sd1 += __shfl_xor(sd1, msk, 64);
        }
        if ((tx & (CH / 4 - 1)) == 0 && r < N) {
            a_s[r * NH + head0] = ss0;
            a_d[r * NH + head0] = sd0;
            a_s[r * NH + head1] = ss1;
            a_d[r * NH + head1] = sd1;
        }
    }
}

__device__ __forceinline__ void gemm_pq_tile48(const float* __restrict__ A,
                                               const float* __restrict__ B,
                                               __half* __restrict__ C,
                                               int N, int K, int M,
                                               int row0, int col0, int tid,
                                               float (*As)[68], float (*Bs)[132]) {
    const int tx = tid & 15, ty = tid >> 4;
    float acc[4][8] = {};
    for (int k0 = 0; k0 < K; k0 += 32) {
        {
            const int a_row = tid >> 2;
            const int a_k   = (tid & 3) * 8;
            const int gr    = row0 + a_row;
            float4 v0 = make_float4(0.f,0.f,0.f,0.f), v1 = make_float4(0.f,0.f,0.f,0.f);
            if (gr < N) {
                const float* ap = A + (size_t)gr * K + k0 + a_k;
                v0 = *(const float4*)ap;
                v1 = *(const float4*)(ap + 4);
            }
            As[a_k + 0][a_row] = v0.x; As[a_k + 1][a_row] = v0.y;
            As[a_k + 2][a_row] = v0.z; As[a_k + 3][a_row] = v0.w;
            As[a_k + 4][a_row] = v1.x; As[a_k + 5][a_row] = v1.y;
            As[a_k + 6][a_row] = v1.z; As[a_k + 7][a_row] = v1.w;
        }
        {
            const int b_k = tid >> 4;
            const int b_c = (tid & 15) * 8;
            const float* bp0 = B + (size_t)(k0 + b_k) * M + col0 + b_c;
            const float* bp1 = B + (size_t)(k0 + b_k + 16) * M + col0 + b_c;
            *(float4*)&Bs[b_k][b_c]          = *(const float4*)bp0;
            *(float4*)&Bs[b_k][b_c + 4]      = *(const float4*)(bp0 + 4);
            *(float4*)&Bs[b_k + 16][b_c]     = *(const float4*)bp1;
            *(float4*)&Bs[b_k + 16][b_c + 4] = *(const float4*)(bp1 + 4);
        }
        __syncthreads();
        #pragma unroll
        for (int kk = 0; kk < 32; ++kk) {
            const float4 a  = *(const float4*)&As[kk][ty * 4];
            const float4 b0 = *(const float4*)&Bs[kk][tx * 4];
            const float4 b1 = *(const float4*)&Bs[kk][64 + tx * 4];
            const float av[4] = {a.x, a.y, a.z, a.w};
            const float bv[8] = {b0.x,b0.y,b0.z,b0.w,b1.x,b1.y,b1.z,b1.w};
            #pragma unroll
            for (int i = 0; i < 4; ++i)
                #pragma unroll
                for (int j = 0; j < 8; ++j)
                    acc[i][j] = fmaf(av[i], bv[j], acc[i][j]);
        }
        __syncthreads();
    }
    const int c0 = col0 + tx * 4;
    const int c1 = c0 + 64;
    #pragma unroll
    for (int i = 0; i < 4; ++i) {
        const int r = row0 + ty * 4 + i;
        if (r < N) {
            __half* cp0 = C + (size_t)r * M + c0;
            __half* cp1 = C + (size_t)r * M + c1;
            *(__half2*)(cp0)     = __halves2half2(__float2half_rn(acc[i][0]), __float2half_rn(acc[i][1]));
            *(__half2*)(cp0 + 2) = __halves2half2(__float2half_rn(acc[i][2]), __float2half_rn(acc[i][3]));
            *(__half2*)(cp1)     = __halves2half2(__float2half_rn(acc[i][4]), __float2half_rn(acc[i][5]));
            *(__half2*)(cp1 + 2) = __halves2half2(__float2half_rn(acc[i][6]), __float2half_rn(acc[i][7]));
        }
    }
}

// ================= softmax+aggregate device helpers (proven bodies) =================

__device__ __forceinline__ void softagg1_node(int n, int lane,
                                              const int* __restrict__ rowptr,
                                              const int* __restrict__ psrc,
                                              const float* __restrict__ a_s,
                                              const float* __restrict__ a_d,
                                              const __half* __restrict__ xl,
                                              const float* __restrict__ bias,
                                              float* __restrict__ out) {
    const int r0 = rowptr[n], r1 = rowptr[n + 1];
    const int hh = lane >> 4;
    const float ad = a_d[n * NH + hh];

    const h4* X = (const h4*)xl;   // row stride 64 h4 units (256 halves)
    float4 A0 = {0,0,0,0}, A1 = {0,0,0,0}, A2 = {0,0,0,0}, A3 = {0,0,0,0};
    float sum = 0.f;
    int j = r0;
    for (; j + 7 < r1; j += 8) {
        const int s0 = psrc[j],     s1 = psrc[j + 1], s2 = psrc[j + 2], s3 = psrc[j + 3];
        const int s4 = psrc[j + 4], s5 = psrc[j + 5], s6 = psrc[j + 6], s7 = psrc[j + 7];
        const float w0 = elw(a_s[s0 * NH + hh] + ad);
        const float w1 = elw(a_s[s1 * NH + hh] + ad);
        const float w2 = elw(a_s[s2 * NH + hh] + ad);
        const float w3 = elw(a_s[s3 * NH + hh] + ad);
        const float w4 = elw(a_s[s4 * NH + hh] + ad);
        const float w5 = elw(a_s[s5 * NH + hh] + ad);
        const float w6 = elw(a_s[s6 * NH + hh] + ad);
        const float w7 = elw(a_s[s7 * NH + hh] + ad);
        sum += ((w0 + w1) + (w2 + w3)) + ((w4 + w5) + (w6 + w7));
        const h4 v0 = X[(size_t)s0 * 64 + lane];
        const h4 v1 = X[(size_t)s1 * 64 + lane];
        const h4 v2 = X[(size_t)s2 * 64 + lane];
        const h4 v3 = X[(size_t)s3 * 64 + lane];
        const h4 v4 = X[(size_t)s4 * 64 + lane];
        const h4 v5 = X[(size_t)s5 * 64 + lane];
        const h4 v6 = X[(size_t)s6 * 64 + lane];
        const h4 v7 = X[(size_t)s7 * 64 + lane];
        float2 l0 = __half22float2(v0.a), m0 = __half22float2(v0.b);
        float2 l1 = __half22float2(v1.a), m1 = __half22float2(v1.b);
        float2 l2 = __half22float2(v2.a), m2 = __half22float2(v2.b);
        float2 l3 = __half22float2(v3.a), m3 = __half22float2(v3.b);
        float2 l4 = __half22float2(v4.a), m4 = __half22float2(v4.b);
        float2 l5 = __half22float2(v5.a), m5 = __half22float2(v5.b);
        float2 l6 = __half22float2(v6.a), m6 = __half22float2(v6.b);
        float2 l7 = __half22float2(v7.a), m7 = __half22float2(v7.b);
        A0.x = fmaf(w0, l0.x, A0.x); A0.y = fmaf(w0, l0.y, A0.y);
        A0.z = fmaf(w0, m0.x, A0.z); A0.w = fmaf(w0, m0.y, A0.w);
        A1.x = fmaf(w1, l1.x, A1.x); A1.y = fmaf(w1, l1.y, A1.y);
        A1.z = fmaf(w1, m1.x, A1.z); A1.w = fmaf(w1, m1.y, A1.w);
        A2.x = fmaf(w2, l2.x, A2.x); A2.y = fmaf(w2, l2.y, A2.y);
        A2.z = fmaf(w2, m2.x, A2.z); A2.w = fmaf(w2, m2.y, A2.w);
        A3.x = fmaf(w3, l3.x, A3.x); A3.y = fmaf(w3, l3.y, A3.y);
        A3.z = fmaf(w3, m3.x, A3.z); A3.w = fmaf(w3, m3.y, A3.w);
        A0.x = fmaf(w4, l4.x, A0.x); A0.y = fmaf(w4, l4.y, A0.y);
        A0.z = fmaf(w4, m4.x, A0.z); A0.w = fmaf(w4, m4.y, A0.w);
        A1.x = fmaf(w5, l5.x, A1.x); A1.y = fmaf(w5, l5.y, A1.y);
        A1.z = fmaf(w5, m5.x, A1.z); A1.w = fmaf(w5, m5.y, A1.w);
        A2.x = fmaf(w6, l6.x, A2.x); A2.y = fmaf(w6, l6.y, A2.y);
        A2.z = fmaf(w6, m6.x, A2.z); A2.w = fmaf(w6, m6.y, A2.w);
        A3.x = fmaf(w7, l7.x, A3.x); A3.y = fmaf(w7, l7.y, A3.y);
        A3.z = fmaf(w7, m7.x, A3.z); A3.w = fmaf(w7, m7.y, A3.w);
    }
    for (; j < r1; ++j) {
        const int s0 = psrc[j];
        const float w0 = elw(a_s[s0 * NH + hh] + ad);
        sum += w0;
        const h4 v0 = X[(size_t)s0 * 64 + lane];
        float2 l0 = __half22float2(v0.a), m0 = __half22float2(v0.b);
        A0.x = fmaf(w0, l0.x, A0.x); A0.y = fmaf(w0, l0.y, A0.y);
        A0.z = fmaf(w0, m0.x, A0.z); A0.w = fmaf(w0, m0.y, A0.w);
    }
    const float inv = 1.f / (sum + 1e-30f);
    float4 t;
    t.x = ((A0.x + A1.x) + (A2.x + A3.x)) * inv;
    t.y = ((A0.y + A1.y) + (A2.y + A3.y)) * inv;
    t.z = ((A0.z + A1.z) + (A2.z + A3.z)) * inv;
    t.w = ((A0.w + A1.w) + (A2.w + A3.w)) * inv;
    #pragma unroll
    for (int msk = 16; msk < 64; msk <<= 1) {
        t.x += __shfl_xor(t.x, msk, 64);
        t.y += __shfl_xor(t.y, msk, 64);
        t.z += __shfl_xor(t.z, msk, 64);
        t.w += __shfl_xor(t.w, msk, 64);
    }
    if (lane < 16) {
        const float4 b = ((const float4*)bias)[lane];
        float4 o;
        o.x = t.x * 0.25f + b.x; o.y = t.y * 0.25f + b.y;
        o.z = t.z * 0.25f + b.z; o.w = t.w * 0.25f + b.w;
        ((float4*)out)[(size_t)n * 16 + lane] = o;
    }
}

__device__ __forceinline__ void softagg2_node(int n, int lane,
                                              const int* __restrict__ rowptr,
                                              const int* __restrict__ psrc,
                                              const float* __restrict__ a_s,
                                              const float* __restrict__ a_d,
                                              float* __restrict__ alpha_p,
                                              float* __restrict__ inv_s,
                                              const __half* __restrict__ xl,
                                              const float* __restrict__ bias,
                                              float* __restrict__ out) {
    const int r0 = rowptr[n], r1 = rowptr[n + 1];
    const int cl = lane & 31, half = lane >> 5, hh = cl >> 3;
    const float ad = a_d[n * NH + hh];
    const bool writer = (cl & 7) == 0;   // one lane per (half, head) writes raw w

    const h4* X = (const h4*)xl;   // row stride 32 h4 units (128 halves)
    float4 A0 = {0,0,0,0}, A1 = {0,0,0,0};
    float sum = 0.f;
    int j = r0;
    for (; j + 7 < r1; j += 8) {
        const int ja = j + half, jc = j + 2 + half, je = j + 4 + half, jg = j + 6 + half;
        const int sa = psrc[ja], sc = psrc[jc], se = psrc[je], sg = psrc[jg];
        const float wa = elw(a_s[sa * NH + hh] + ad);
        const float wc = elw(a_s[sc * NH + hh] + ad);
        const float we = elw(a_s[se * NH + hh] + ad);
        const float wg = elw(a_s[sg * NH + hh] + ad);
        if (writer) {
            alpha_p[ja * NH + hh] = wa; alpha_p[jc * NH + hh] = wc;
            alpha_p[je * NH + hh] = we; alpha_p[jg * NH + hh] = wg;
        }
        sum += (wa + wc) + (we + wg);
        const h4 va = X[(size_t)sa * 32 + cl];
        const h4 vc = X[(size_t)sc * 32 + cl];
        const h4 ve = X[(size_t)se * 32 + cl];
        const h4 vg = X[(size_t)sg * 32 + cl];
        const float2 la = __half22float2(va.a), ma = __half22float2(va.b);
        const float2 lc = __half22float2(vc.a), mc = __half22float2(vc.b);
        const float2 le = __half22float2(ve.a), me = __half22float2(ve.b);
        const float2 lg = __half22float2(vg.a), mg = __half22float2(vg.b);
        A0.x = fmaf(wa, la.x, A0.x); A0.y = fmaf(wa, la.y, A0.y);
        A0.z = fmaf(wa, ma.x, A0.z); A0.w = fmaf(wa, ma.y, A0.w);
        A1.x = fmaf(wc, lc.x, A1.x); A1.y = fmaf(wc, lc.y, A1.y);
        A1.z = fmaf(wc, mc.x, A1.z); A1.w = fmaf(wc, mc.y, A1.w);
        A0.x = fmaf(we, le.x, A0.x); A0.y = fmaf(we, le.y, A0.y);
        A0.z = fmaf(we, me.x, A0.z); A0.w = fmaf(we, me.y, A0.w);
        A1.x = fmaf(wg, lg.x, A1.x); A1.y = fmaf(wg, lg.y, A1.y);
        A1.z = fmaf(wg, mg.x, A1.z); A1.w = fmaf(wg, mg.y, A1.w);
    }
    for (; j < r1; j += 2) {
        const int ja = j + half;
        const bool valid = ja < r1;
        const int sa = psrc[valid ? ja : r0];
        float wa = 0.f;
        if (valid) {
            wa = elw(a_s[sa * NH + hh] + ad);
            if (writer) alpha_p[ja * NH + hh] = wa;
        }
        sum += wa;
        const h4 va = X[(size_t)sa * 32 + cl];
        const float2 la = __half22float2(va.a), ma = __half22float2(va.b);
        A0.x = fmaf(wa, la.x, A0.x); A0.y = fmaf(wa, la.y, A0.y);
        A0.z = fmaf(wa, ma.x, A0.z); A0.w = fmaf(wa, ma.y, A0.w);
    }
    // merge halves' partial sums, then normalize
    sum += __shfl_xor(sum, 32, 64);
    const float inv = 1.f / (sum + 1e-30f);
    if (writer && half == 0) inv_s[n * NH + hh] = inv;

    float4 t;
    t.x = A0.x + A1.x; t.y = A0.y + A1.y; t.z = A0.z + A1.z; t.w = A0.w + A1.w;
    t.x += __shfl_xor(t.x, 32, 64);
    t.y += __shfl_xor(t.y, 32, 64);
    t.z += __shfl_xor(t.z, 32, 64);
    t.w += __shfl_xor(t.w, 32, 64);
    t.x *= inv; t.y *= inv; t.z *= inv; t.w *= inv;
    #pragma unroll
    for (int q = 0; q < 2; ++q) {
        const int msk = (q == 0) ? 8 : 16;
        t.x += __shfl_xor(t.x, msk, 64);
        t.y += __shfl_xor(t.y, msk, 64);
        t.z += __shfl_xor(t.z, msk, 64);
        t.w += __shfl_xor(t.w, msk, 64);
    }
    if (lane < 8) {
        const float4 b = ((const float4*)bias)[lane];
        float4 o;
        o.x = t.x * 0.25f + b.x; o.y = t.y * 0.25f + b.y;
        o.z = t.z * 0.25f + b.z; o.w = t.w * 0.25f + b.w;
        ((float4*)out)[(size_t)n * 8 + lane] = o;
    }
}

// ================= kernels =================

__global__ __launch_bounds__(256) void count_deg_k(const int* __restrict__ ei,
                                                   int* __restrict__ deg) {
    const int e = blockIdx.x * 256 + threadIdx.x;
    if (e < EE) atomicAdd(&deg[ei[EE + e]], 1);
}

__global__ __launch_bounds__(256) void pack_w1_k(const float* __restrict__ mW1,
                                                 float* __restrict__ W1pq) {
    const int idx = blockIdx.x * 256 + threadIdx.x;
    if (idx >= 32 * 128) return;
    const int k = idx >> 7, j = idx & 127;
    W1pq[idx] = (j < 64) ? mW1[k * 64 + j] : mW1[(36 + k) * 64 + (j - 64)];
}

template <int CH, bool HOUT>
__global__ __launch_bounds__(256) void gemm_att48_k(const float* __restrict__ A,
                                                    const float* __restrict__ B,
                                                    void* __restrict__ Cv,
                                                    const float* __restrict__ att_s,
                                                    const float* __restrict__ att_d,
                                                    float* __restrict__ a_s,
                                                    float* __restrict__ a_d,
                                                    int N, int K, int M) {
    __shared__ float As[32][68];
    __shared__ float Bs[32][132];
    gemm_att_tile48<CH, HOUT>(A, B, Cv, att_s, att_d, a_s, a_d, N, K, M,
                              blockIdx.x * 64, blockIdx.y * 128, threadIdx.x, As, Bs);
}

__global__ __launch_bounds__(256) void gemm_pq48_k(const float* __restrict__ A,
                                                   const float* __restrict__ B,
                                                   __half* __restrict__ C,
                                                   int N, int K, int M) {
    __shared__ float As[32][68];
    __shared__ float Bs[32][132];
    gemm_pq_tile48(A, B, C, N, K, M, blockIdx.x * 64, blockIdx.y * 128, threadIdx.x, As, Bs);
}

// ---- multi-block exclusive scan (3 phases; HW-verified logic) ----
__global__ __launch_bounds__(256) void scan1_k(const int* __restrict__ deg,
                                               int* __restrict__ bsum) {
    __shared__ int sw[4];
    const int tid = threadIdx.x, lane = tid & 63, wv = tid >> 6;
    const int i = blockIdx.x * 256 + tid;
    int s = (i < NN) ? deg[i] : 0;
    #pragma unroll
    for (int d = 1; d < 64; d <<= 1) s += __shfl_xor(s, d, 64);
    if (lane == 0) sw[wv] = s;
    __syncthreads();
    if (tid == 0) bsum[blockIdx.x] = sw[0] + sw[1] + sw[2] + sw[3];
}

__global__ __launch_bounds__(256) void scan2_k(const int* __restrict__ bsum,
                                               int* __restrict__ boff) {
    __shared__ int sw[8];
    const int tid = threadIdx.x, lane = tid & 63, wv = tid >> 6;
    int v = (tid < NCH) ? bsum[tid] : 0;
    int incl = v;
    #pragma unroll
    for (int d = 1; d < 64; d <<= 1) {
        int t = __shfl_up(incl, d, 64);
        if (lane >= d) incl += t;
    }
    if (lane == 63) sw[wv] = incl;
    __syncthreads();
    if (wv == 0 && lane < 4) {
        int s4 = sw[lane];
        #pragma unroll
        for (int d = 1; d < 4; d <<= 1) {
            int t = __shfl_up(s4, d, 64);
            if (lane >= d) s4 += t;
        }
        sw[lane + 4] = s4;
    }
    __syncthreads();
    const int woff = (wv > 0) ? sw[wv - 1 + 4] : 0;
    if (tid < NCH) boff[tid] = woff + incl - v;
}

__global__ __launch_bounds__(256) void scan3_k(const int* __restrict__ deg,
                                               const int* __restrict__ boff,
                                               int* __restrict__ rowptr,
                                               int* __restrict__ cursor) {
    __shared__ int sw[8];
    const int tid = threadIdx.x, lane = tid & 63, wv = tid >> 6;
    const int c = blockIdx.x;
    const int i = c * 256 + tid;
    int v = (i < NN) ? deg[i] : 0;
    int incl = v;
    #pragma unroll
    for (int d = 1; d < 64; d <<= 1) {
        int t = __shfl_up(incl, d, 64);
        if (lane >= d) incl += t;
    }
    if (lane == 63) sw[wv] = incl;
    __syncthreads();
    if (wv == 0 && lane < 4) {
        int s4 = sw[lane];
        #pragma unroll
        for (int d = 1; d < 4; d <<= 1) {
            int t = __shfl_up(s4, d, 64);
            if (lane >= d) s4 += t;
        }
        sw[lane + 4] = s4;
    }
    __syncthreads();
    const int excl = boff[c] + ((wv > 0) ? sw[wv - 1 + 4] : 0) + incl - v;
    if (i < NN) { rowptr[i] = excl; cursor[i] = excl; }
    if (c == 0 && tid == 0) rowptr[NN] = EE;
}

__global__ __launch_bounds__(256) void scatter_perm_k(const int* __restrict__ ei,
                                                      int* __restrict__ cursor,
                                                      int* __restrict__ perm,
                                                      int* __restrict__ psrc,
                                                      int* __restrict__ pdst) {
    const int e = blockIdx.x * 256 + threadIdx.x;
    if (e >= EE) return;
    const int d = ei[EE + e];
    const int p = atomicAdd(&cursor[d], 1);
    perm[p] = e;
    psrc[p] = ei[e];
    pdst[p] = d;
}

__global__ __launch_bounds__(256) void softagg1h_k(const int* __restrict__ rowptr,
                                                   const int* __restrict__ psrc,
                                                   const float* __restrict__ a_s,
                                                   const float* __restrict__ a_d,
                                                   const __half* __restrict__ xl,
                                                   const float* __restrict__ bias,
                                                   float* __restrict__ out) {
    const int n = blockIdx.x * 4 + (threadIdx.x >> 6);
    if (n >= NN) return;
    softagg1_node(n, threadIdx.x & 63, rowptr, psrc, a_s, a_d, xl, bias, out);
}

__global__ __launch_bounds__(256) void softagg2h_k(const int* __restrict__ rowptr,
                                                   const int* __restrict__ psrc,
                                                   const float* __restrict__ a_s,
                                                   const float* __restrict__ a_d,
                                                   float* __restrict__ alpha_p,
                                                   float* __restrict__ inv_s,
                                                   const __half* __restrict__ xl,
                                                   const float* __restrict__ bias,
                                                   float* __restrict__ out) {
    const int n = blockIdx.x * 4 + (threadIdx.x >> 6);
    if (n >= NN) return;
    softagg2_node(n, threadIdx.x & 63, rowptr, psrc, a_s, a_d, alpha_p, inv_s, xl, bias, out);
}

__global__ __launch_bounds__(256) void edge_mlp_k(const __half* __restrict__ PQ,
                                                  const float* __restrict__ alpha_p,
                                                  const float* __restrict__ inv_s,
                                                  const int* __restrict__ psrc,
                                                  const int* __restrict__ pdst,
                                                  const int* __restrict__ perm,
                                                  const float* __restrict__ mW1,
                                                  const float* __restrict__ mb1,
                                                  const float* __restrict__ mW2,
                                                  const float* __restrict__ mb2,
                                                  float* __restrict__ out) {
    const int lane = threadIdx.x & 63, wvv = threadIdx.x >> 6;
    const int g = lane >> 4, c = lane & 15;

    const float4 wa0 = *(const float4*)&mW1[32 * 64 + c * 4];
    const float4 wa1 = *(const float4*)&mW1[33 * 64 + c * 4];
    const float4 wa2 = *(const float4*)&mW1[34 * 64 + c * 4];
    const float4 wa3 = *(const float4*)&mW1[35 * 64 + c * 4];
    const float4 b1v = *(const float4*)&mb1[c * 4];
    const float4 w2a = *(const float4*)&mW2[c * 8];
    const float4 w2b = *(const float4*)&mW2[c * 8 + 4];
    const float bo0 = mb2[0], bo1 = mb2[1];

    const h4* PQ4 = (const h4*)PQ;
    const int gw = blockIdx.x * 4 + wvv;
    const int stride4 = gridDim.x * 4 * 4;

    for (int jb = gw * 4; jb < EE; jb += stride4) {
        const int j = jb + g;
        const int s = psrc[j];
        const int d = pdst[j];
        const float4 ar = *(const float4*)&alpha_p[(size_t)j * 4];
        const float4 iv = *(const float4*)&inv_s[(size_t)d * 4];
        const float al0 = ar.x * iv.x, al1 = ar.y * iv.y;
        const float al2 = ar.z * iv.z, al3 = ar.w * iv.w;
        const h4 ph = PQ4[(size_t)s * 32 + c];
        const h4 qh = PQ4[(size_t)d * 32 + 16 + c];
        const float2 pl = __half22float2(ph.a), pm = __half22float2(ph.b);
        const float2 ql = __half22float2(qh.a), qm = __half22float2(qh.b);
        float4 h;
        h.x = pl.x + ql.x + b1v.x; h.y = pl.y + ql.y + b1v.y;
        h.z = pm.x + qm.x + b1v.z; h.w = pm.y + qm.y + b1v.w;
        h.x = fmaf(al0, wa0.x, h.x); h.y = fmaf(al0, wa0.y, h.y);
        h.z = fmaf(al0, wa0.z, h.z); h.w = fmaf(al0, wa0.w, h.w);
        h.x = fmaf(al1, wa1.x, h.x); h.y = fmaf(al1, wa1.y, h.y);
        h.z = fmaf(al1, wa1.z, h.z); h.w = fmaf(al1, wa1.w, h.w);
        h.x = fmaf(al2, wa2.x, h.x); h.y = fmaf(al2, wa2.y, h.y);
        h.z = fmaf(al2, wa2.z, h.z); h.w = fmaf(al2, wa2.w, h.w);
        h.x = fmaf(al3, wa3.x, h.x); h.y = fmaf(al3, wa3.y, h.y);
        h.z = fmaf(al3, wa3.z, h.z); h.w = fmaf(al3, wa3.w, h.w);
        h.x = fmaxf(h.x, 0.f); h.y = fmaxf(h.y, 0.f);
        h.z = fmaxf(h.z, 0.f); h.w = fmaxf(h.w, 0.f);

        float v0 = h.x * w2a.x + h.y * w2a.z + h.z * w2b.x + h.w * w2b.z;
        float v1 = h.x * w2a.y + h.y * w2a.w + h.z * w2b.y + h.w * w2b.w;
        #pragma unroll
        for (int msk = 1; msk < 16; msk <<= 1) {
            v0 += __shfl_xor(v0, msk, 64);
            v1 += __shfl_xor(v1, msk, 64);
        }
        if (c == 0)
            *(float2*)&out[(size_t)perm[j] * 2] = make_float2(v0 + bo0, v1 + bo1);
    }
}

extern "C" void kernel_launch(void* const* d_in, const int* in_sizes, int n_in,
                              void* d_out, int out_size, void* d_ws, size_t ws_size,
                              hipStream_t stream) {
    const float* x        = (const float*)d_in[0];
    const int*   ei       = (const int*)d_in[1];
    // d_in[2] edge_attr: unused (edge_dim=None). d_in[3] flag: unused.
    const float* W1       = (const float*)d_in[4];
    const float* att1_src = (const float*)d_in[5];
    const float* att1_dst = (const float*)d_in[6];
    const float* b1       = (const float*)d_in[7];
    const float* W3       = (const float*)d_in[8];
    const float* att3_src = (const float*)d_in[9];
    const float* att3_dst = (const float*)d_in[10];
    const float* b3       = (const float*)d_in[11];
    const float* mW1      = (const float*)d_in[12];
    const float* mb1      = (const float*)d_in[13];
    const float* mW2      = (const float*)d_in[14];
    const float* mb2      = (const float*)d_in[15];

    float* out_nodes = (float*)d_out;               // [N,32]
    float* out_edges = out_nodes + (size_t)NN * 32; // [E,2]

    // workspace layout (floats/ints)
    float* ws = (float*)d_ws;
    __half*   xlh     = (__half*)ws;                  // N*256 halves (layer-1 GEMM out)
    __half*   xl2h    = (__half*)ws;                  // N*128 halves (layer-2 GEMM out)
    __half*   PQh     = (__half*)ws;                  // N*128 halves, after xl2h dead
    float*    h1      = ws + 12800000;                // N*64
    float*    alpha_p = ws + 16000000;                // E*4 (CSR-order raw w, layer 2)
    float*    a_s     = ws + 25600000;                // N*4
    float*    a_d     = ws + 25800000;                // N*4
    float*    W1pq    = ws + 26000000;                // 32*128
    float*    inv_s   = ws + 26100000;                // N*4
    int*      bsum    = (int*)(ws + 26300000);        // NCH
    int*      boff    = (int*)(ws + 26301000);        // NCH
    int*      deg     = (int*)(ws + 26400000);        // N
    int*      cursor  = (int*)(ws + 26450000);        // N
    int*      rowptr  = (int*)(ws + 26500000);        // N+1
    int*      perm    = (int*)(ws + 26550008);        // E
    int*      psrc    = (int*)(ws + 27350008);        // E
    int*      pdst    = (int*)(ws + 28150008);        // E

    const int NB4 = (NN + 3) / 4;

    // 1) CSR build front half
    hipMemsetAsync(deg, 0, (size_t)NN * 4, stream);
    count_deg_k<<<EB, 256, 0, stream>>>(ei, deg);
    pack_w1_k<<<16, 256, 0, stream>>>(mW1, W1pq);
    // 2) layer-1 GEMM on MATRIX CORES (split-bf16, fp32-grade)
    gemm1_mfma_k<<<dim3(GR64, 4), 256, 0, stream>>>(x, W1, xlh, att1_src, att1_dst,
                                                    a_s, a_d);
    // 3) multi-block exclusive scan -> rowptr/cursor
    scan1_k<<<NCH, 256, 0, stream>>>(deg, bsum);
    scan2_k<<<1, 256, 0, stream>>>(bsum, boff);
    scan3_k<<<NCH, 256, 0, stream>>>(deg, boff, rowptr, cursor);
    // 4) scatter edges into CSR order
    scatter_perm_k<<<EB, 256, 0, stream>>>(ei, cursor, perm, psrc, pdst);
    // 5) layer-1 softmax+aggregate
    softagg1h_k<<<NB4, 256, 0, stream>>>(rowptr, psrc, a_s, a_d, xlh, b1, h1);
    // 6) layer-2 GEMM (vector path, K=64)
    gemm_att48_k<32, true><<<dim3(GR64, 1), 256, 0, stream>>>(h1, W3, xl2h,
                                                              att3_src, att3_dst,
                                                              a_s, a_d, NN, 64, NH * 32);
    // 7) layer-2 softmax+aggregate
    softagg2h_k<<<NB4, 256, 0, stream>>>(rowptr, psrc, a_s, a_d, alpha_p, inv_s, xl2h, b3,
                                         out_nodes);
    // 8) PQ GEMM (K=32 single step; xl2h dead -> PQh aliases it)
    gemm_pq48_k<<<dim3(GR64, 1), 256, 0, stream>>>(out_nodes, W1pq, PQh, NN, 32, 128);
    // 9) edge MLP
    edge_mlp_k<<<2048, 256, 0, stream>>>(PQh, alpha_p, inv_s, psrc, pdst, perm,
                                         mW1, mb1, mW2, mb2, out_edges);
}

// Round 11
// 416.720 us; speedup vs baseline: 1.0799x; 1.0243x over previous
//
#include <hip/hip_runtime.h>
#include <hip/hip_fp16.h>

// Problem constants
constexpr int NN   = 50000;
constexpr int EE   = 800000;
constexpr int INF  = 128;   // input feat
constexpr int NH   = 4;     // heads
constexpr int GR64 = (NN + 63) / 64;        // 782 row tiles
constexpr int EB   = (EE + 255) / 256;      // 3125 edge blocks
constexpr int NCH  = (NN + 255) / 256;      // 196 scan chunks

struct __align__(8) h4 { __half2 a, b; };   // 4 halves = 8 bytes

typedef short bf16x8 __attribute__((ext_vector_type(8)));
typedef float f32x4v __attribute__((ext_vector_type(4)));

__device__ __forceinline__ float elw(float a) {
    a = (a > 0.f) ? a : 0.2f * a;          // leaky_relu(0.2)
    return __expf(a);                       // exp without max-sub (scores bounded)
}

__device__ __forceinline__ short bf16_hi(float x) {
    return (short)(__float_as_uint(x) >> 16);   // truncate to bf16
}
__device__ __forceinline__ float bf16_back(short h) {
    return __uint_as_float(((unsigned)(unsigned short)h) << 16);
}

// ======== Layer-1 GEMM on MATRIX CORES: split-bf16 (hi+lo), fp32-grade (R10-proven) ====
__global__ __launch_bounds__(256) void gemm1_mfma_k(const float* __restrict__ A,   // x [N][128]
                                                    const float* __restrict__ B,   // W1 [128][256]
                                                    __half* __restrict__ C,        // xlh [N][256]
                                                    const float* __restrict__ att_s,
                                                    const float* __restrict__ att_d,
                                                    float* __restrict__ a_s,
                                                    float* __restrict__ a_d) {
    __shared__ short Ah[64][72], Al[64][72];
    __shared__ short Bh[64][72], Bl[64][72];   // transposed: [col][k_local]
    const int tid  = threadIdx.x;
    const int lane = tid & 63, w = tid >> 6;
    const int row0 = blockIdx.x * 64;
    const int head = blockIdx.y;              // 64 cols per head
    const int c0   = head * 64;

    const int rl = lane & 15, gq = lane >> 4;

    f32x4v acc0 = {0,0,0,0}, acc1 = {0,0,0,0}, acc2 = {0,0,0,0}, acc3 = {0,0,0,0};

    for (int ks = 0; ks < 2; ++ks) {
        {
            const int ar = tid >> 2;               // 0..63
            const int kb = (tid & 3) * 4;          // 0,4,8,12
            const int grow = row0 + ar;
            #pragma unroll
            for (int pass = 0; pass < 4; ++pass) {
                const int kl = kb + pass * 16;     // 0..63
                float4 v = make_float4(0.f, 0.f, 0.f, 0.f);
                if (grow < NN) v = *(const float4*)(A + (size_t)grow * 128 + ks * 64 + kl);
                short4 hi, lo;
                hi.x = bf16_hi(v.x); lo.x = bf16_hi(v.x - bf16_back(hi.x));
                hi.y = bf16_hi(v.y); lo.y = bf16_hi(v.y - bf16_back(hi.y));
                hi.z = bf16_hi(v.z); lo.z = bf16_hi(v.z - bf16_back(hi.z));
                hi.w = bf16_hi(v.w); lo.w = bf16_hi(v.w - bf16_back(hi.w));
                *(short4*)&Ah[ar][kl] = hi;
                *(short4*)&Al[ar][kl] = lo;
            }
        }
        {
            const int c  = lane;                   // 0..63
            const int kb = w * 16;                 // 16 k per wave
            #pragma unroll
            for (int chunk = 0; chunk < 2; ++chunk) {
                short hi8[8], lo8[8];
                #pragma unroll
                for (int i = 0; i < 8; ++i) {
                    const int kl = kb + chunk * 8 + i;
                    const float v = B[(size_t)(ks * 64 + kl) * 256 + c0 + c];
                    hi8[i] = bf16_hi(v);
                    lo8[i] = bf16_hi(v - bf16_back(hi8[i]));
                }
                *(bf16x8*)&Bh[c][kb + chunk * 8] =
                    (bf16x8){hi8[0],hi8[1],hi8[2],hi8[3],hi8[4],hi8[5],hi8[6],hi8[7]};
                *(bf16x8*)&Bl[c][kb + chunk * 8] =
                    (bf16x8){lo8[0],lo8[1],lo8[2],lo8[3],lo8[4],lo8[5],lo8[6],lo8[7]};
            }
        }
        __syncthreads();

        bf16x8 aH0 = *(const bf16x8*)&Ah[w * 16 + rl][gq * 8];
        bf16x8 aH1 = *(const bf16x8*)&Ah[w * 16 + rl][32 + gq * 8];
        bf16x8 aL0 = *(const bf16x8*)&Al[w * 16 + rl][gq * 8];
        bf16x8 aL1 = *(const bf16x8*)&Al[w * 16 + rl][32 + gq * 8];

        #pragma unroll
        for (int cf = 0; cf < 4; ++cf) {
            const int bc = cf * 16 + rl;
            bf16x8 bH0 = *(const bf16x8*)&Bh[bc][gq * 8];
            bf16x8 bH1 = *(const bf16x8*)&Bh[bc][32 + gq * 8];
            bf16x8 bL0 = *(const bf16x8*)&Bl[bc][gq * 8];
            bf16x8 bL1 = *(const bf16x8*)&Bl[bc][32 + gq * 8];
            f32x4v t = (cf == 0) ? acc0 : (cf == 1) ? acc1 : (cf == 2) ? acc2 : acc3;
            t = __builtin_amdgcn_mfma_f32_16x16x32_bf16(aH0, bH0, t, 0, 0, 0);
            t = __builtin_amdgcn_mfma_f32_16x16x32_bf16(aL0, bH0, t, 0, 0, 0);
            t = __builtin_amdgcn_mfma_f32_16x16x32_bf16(aH0, bL0, t, 0, 0, 0);
            t = __builtin_amdgcn_mfma_f32_16x16x32_bf16(aH1, bH1, t, 0, 0, 0);
            t = __builtin_amdgcn_mfma_f32_16x16x32_bf16(aL1, bH1, t, 0, 0, 0);
            t = __builtin_amdgcn_mfma_f32_16x16x32_bf16(aH1, bL1, t, 0, 0, 0);
            if (cf == 0) acc0 = t; else if (cf == 1) acc1 = t;
            else if (cf == 2) acc2 = t; else acc3 = t;
        }
        __syncthreads();
    }

    float sS[4] = {0.f, 0.f, 0.f, 0.f};
    float sD[4] = {0.f, 0.f, 0.f, 0.f};
    #pragma unroll
    for (int cf = 0; cf < 4; ++cf) {
        const f32x4v t = (cf == 0) ? acc0 : (cf == 1) ? acc1 : (cf == 2) ? acc2 : acc3;
        const int gcol = c0 + cf * 16 + rl;
        const float atS = att_s[gcol];
        const float atD = att_d[gcol];
        #pragma unroll
        for (int r = 0; r < 4; ++r) {
            const int grow = row0 + w * 16 + gq * 4 + r;
            if (grow < NN) C[(size_t)grow * 256 + gcol] = __float2half_rn(t[r]);
            sS[r] = fmaf(t[r], atS, sS[r]);
            sD[r] = fmaf(t[r], atD, sD[r]);
        }
    }
    #pragma unroll
    for (int r = 0; r < 4; ++r) {
        #pragma unroll
        for (int msk = 1; msk < 16; msk <<= 1) {
            sS[r] += __shfl_xor(sS[r], msk, 64);
            sD[r] += __shfl_xor(sD[r], msk, 64);
        }
    }
    if (rl == 0) {
        #pragma unroll
        for (int r = 0; r < 4; ++r) {
            const int grow = row0 + w * 16 + gq * 4 + r;
            if (grow < NN) {
                a_s[grow * NH + head] = sS[r];
                a_d[grow * NH + head] = sD[r];
            }
        }
    }
}

// ======== Layer-2 GEMM on MATRIX CORES: [N,64]x[64,128], CH=32 (2 heads/tile) ========
__global__ __launch_bounds__(256) void gemm2_mfma_k(const float* __restrict__ A,   // h1 [N][64]
                                                    const float* __restrict__ B,   // W3 [64][128]
                                                    __half* __restrict__ C,        // xl2h [N][128]
                                                    const float* __restrict__ att_s,
                                                    const float* __restrict__ att_d,
                                                    float* __restrict__ a_s,
                                                    float* __restrict__ a_d) {
    __shared__ short Ah[64][72], Al[64][72];
    __shared__ short Bh[64][72], Bl[64][72];   // transposed: [col][k]
    const int tid  = threadIdx.x;
    const int lane = tid & 63, w = tid >> 6;
    const int row0 = blockIdx.x * 64;
    const int c0   = blockIdx.y * 64;          // cols c0..c0+63 -> heads c0/32, c0/32+1
    const int rl = lane & 15, gq = lane >> 4;

    // stage A (64 rows x 64 k), split hi/lo
    {
        const int ar = tid >> 2;
        const int kb = (tid & 3) * 4;
        const int grow = row0 + ar;
        #pragma unroll
        for (int pass = 0; pass < 4; ++pass) {
            const int kl = kb + pass * 16;
            float4 v = make_float4(0.f, 0.f, 0.f, 0.f);
            if (grow < NN) v = *(const float4*)(A + (size_t)grow * 64 + kl);
            short4 hi, lo;
            hi.x = bf16_hi(v.x); lo.x = bf16_hi(v.x - bf16_back(hi.x));
            hi.y = bf16_hi(v.y); lo.y = bf16_hi(v.y - bf16_back(hi.y));
            hi.z = bf16_hi(v.z); lo.z = bf16_hi(v.z - bf16_back(hi.z));
            hi.w = bf16_hi(v.w); lo.w = bf16_hi(v.w - bf16_back(hi.w));
            *(short4*)&Ah[ar][kl] = hi;
            *(short4*)&Al[ar][kl] = lo;
        }
    }
    // stage B transposed (64 k x 64 cols)
    {
        const int c  = lane;
        const int kb = w * 16;
        #pragma unroll
        for (int chunk = 0; chunk < 2; ++chunk) {
            short hi8[8], lo8[8];
            #pragma unroll
            for (int i = 0; i < 8; ++i) {
                const int kl = kb + chunk * 8 + i;
                const float v = B[(size_t)kl * 128 + c0 + c];
                hi8[i] = bf16_hi(v);
                lo8[i] = bf16_hi(v - bf16_back(hi8[i]));
            }
            *(bf16x8*)&Bh[c][kb + chunk * 8] =
                (bf16x8){hi8[0],hi8[1],hi8[2],hi8[3],hi8[4],hi8[5],hi8[6],hi8[7]};
            *(bf16x8*)&Bl[c][kb + chunk * 8] =
                (bf16x8){lo8[0],lo8[1],lo8[2],lo8[3],lo8[4],lo8[5],lo8[6],lo8[7]};
        }
    }
    __syncthreads();

    bf16x8 aH0 = *(const bf16x8*)&Ah[w * 16 + rl][gq * 8];
    bf16x8 aH1 = *(const bf16x8*)&Ah[w * 16 + rl][32 + gq * 8];
    bf16x8 aL0 = *(const bf16x8*)&Al[w * 16 + rl][gq * 8];
    bf16x8 aL1 = *(const bf16x8*)&Al[w * 16 + rl][32 + gq * 8];

    f32x4v acc0 = {0,0,0,0}, acc1 = {0,0,0,0}, acc2 = {0,0,0,0}, acc3 = {0,0,0,0};
    #pragma unroll
    for (int cf = 0; cf < 4; ++cf) {
        const int bc = cf * 16 + rl;
        bf16x8 bH0 = *(const bf16x8*)&Bh[bc][gq * 8];
        bf16x8 bH1 = *(const bf16x8*)&Bh[bc][32 + gq * 8];
        bf16x8 bL0 = *(const bf16x8*)&Bl[bc][gq * 8];
        bf16x8 bL1 = *(const bf16x8*)&Bl[bc][32 + gq * 8];
        f32x4v t = (cf == 0) ? acc0 : (cf == 1) ? acc1 : (cf == 2) ? acc2 : acc3;
        t = __builtin_amdgcn_mfma_f32_16x16x32_bf16(aH0, bH0, t, 0, 0, 0);
        t = __builtin_amdgcn_mfma_f32_16x16x32_bf16(aL0, bH0, t, 0, 0, 0);
        t = __builtin_amdgcn_mfma_f32_16x16x32_bf16(aH0, bL0, t, 0, 0, 0);
        t = __builtin_amdgcn_mfma_f32_16x16x32_bf16(aH1, bH1, t, 0, 0, 0);
        t = __builtin_amdgcn_mfma_f32_16x16x32_bf16(aL1, bH1, t, 0, 0, 0);
        t = __builtin_amdgcn_mfma_f32_16x16x32_bf16(aH1, bL1, t, 0, 0, 0);
        if (cf == 0) acc0 = t; else if (cf == 1) acc1 = t;
        else if (cf == 2) acc2 = t; else acc3 = t;
    }

    // epilogue: cf 0,1 -> head0 (c0/32); cf 2,3 -> head1
    const int h0 = c0 >> 5, h1 = h0 + 1;
    float sS0[4] = {0,0,0,0}, sD0[4] = {0,0,0,0};
    float sS1[4] = {0,0,0,0}, sD1[4] = {0,0,0,0};
    #pragma unroll
    for (int cf = 0; cf < 4; ++cf) {
        const f32x4v t = (cf == 0) ? acc0 : (cf == 1) ? acc1 : (cf == 2) ? acc2 : acc3;
        const int gcol = c0 + cf * 16 + rl;
        const float atS = att_s[gcol];       // [4][32] flat: head*32+pos == gcol
        const float atD = att_d[gcol];
        #pragma unroll
        for (int r = 0; r < 4; ++r) {
            const int grow = row0 + w * 16 + gq * 4 + r;
            if (grow < NN) C[(size_t)grow * 128 + gcol] = __float2half_rn(t[r]);
            if (cf < 2) { sS0[r] = fmaf(t[r], atS, sS0[r]); sD0[r] = fmaf(t[r], atD, sD0[r]); }
            else        { sS1[r] = fmaf(t[r], atS, sS1[r]); sD1[r] = fmaf(t[r], atD, sD1[r]); }
        }
    }
    #pragma unroll
    for (int r = 0; r < 4; ++r) {
        #pragma unroll
        for (int msk = 1; msk < 16; msk <<= 1) {
            sS0[r] += __shfl_xor(sS0[r], msk, 64);
            sD0[r] += __shfl_xor(sD0[r], msk, 64);
            sS1[r] += __shfl_xor(sS1[r], msk, 64);
            sD1[r] += __shfl_xor(sD1[r], msk, 64);
        }
    }
    if (rl == 0) {
        #pragma unroll
        for (int r = 0; r < 4; ++r) {
            const int grow = row0 + w * 16 + gq * 4 + r;
            if (grow < NN) {
                a_s[grow * NH + h0] = sS0[r];
                a_d[grow * NH + h0] = sD0[r];
                a_s[grow * NH + h1] = sS1[r];
                a_d[grow * NH + h1] = sD1[r];
            }
        }
    }
}

// ======== PQ GEMM on MATRIX CORES: [N,32]x[32,128], K=32 single fragment ========
__global__ __launch_bounds__(256) void gemmpq_mfma_k(const float* __restrict__ A,   // out_nodes [N][32]
                                                     const float* __restrict__ B,   // W1pq [32][128]
                                                     __half* __restrict__ C) {      // PQh [N][128]
    __shared__ short Ah[64][40], Al[64][40];
    __shared__ short Bh[64][40], Bl[64][40];   // transposed: [col][k]
    const int tid  = threadIdx.x;
    const int lane = tid & 63, w = tid >> 6;
    const int row0 = blockIdx.x * 64;
    const int c0   = blockIdx.y * 64;
    const int rl = lane & 15, gq = lane >> 4;

    // stage A (64 rows x 32 k)
    {
        const int ar = tid >> 2;
        const int kb = (tid & 3) * 4;
        const int grow = row0 + ar;
        #pragma unroll
        for (int pass = 0; pass < 2; ++pass) {
            const int kl = kb + pass * 16;     // 0..31
            float4 v = make_float4(0.f, 0.f, 0.f, 0.f);
            if (grow < NN) v = *(const float4*)(A + (size_t)grow * 32 + kl);
            short4 hi, lo;
            hi.x = bf16_hi(v.x); lo.x = bf16_hi(v.x - bf16_back(hi.x));
            hi.y = bf16_hi(v.y); lo.y = bf16_hi(v.y - bf16_back(hi.y));
            hi.z = bf16_hi(v.z); lo.z = bf16_hi(v.z - bf16_back(hi.z));
            hi.w = bf16_hi(v.w); lo.w = bf16_hi(v.w - bf16_back(hi.w));
            *(short4*)&Ah[ar][kl] = hi;
            *(short4*)&Al[ar][kl] = lo;
        }
    }
    // stage B transposed (32 k x 64 cols; wave w covers k = w*8..w*8+7)
    {
        const int c = lane;
        short hi8[8], lo8[8];
        #pragma unroll
        for (int i = 0; i < 8; ++i) {
            const int kl = w * 8 + i;
            const float v = B[(size_t)kl * 128 + c0 + c];
            hi8[i] = bf16_hi(v);
            lo8[i] = bf16_hi(v - bf16_back(hi8[i]));
        }
        *(bf16x8*)&Bh[c][w * 8] =
            (bf16x8){hi8[0],hi8[1],hi8[2],hi8[3],hi8[4],hi8[5],hi8[6],hi8[7]};
        *(bf16x8*)&Bl[c][w * 8] =
            (bf16x8){lo8[0],lo8[1],lo8[2],lo8[3],lo8[4],lo8[5],lo8[6],lo8[7]};
    }
    __syncthreads();

    bf16x8 aH = *(const bf16x8*)&Ah[w * 16 + rl][gq * 8];
    bf16x8 aL = *(const bf16x8*)&Al[w * 16 + rl][gq * 8];

    #pragma unroll
    for (int cf = 0; cf < 4; ++cf) {
        const int bc = cf * 16 + rl;
        bf16x8 bH = *(const bf16x8*)&Bh[bc][gq * 8];
        bf16x8 bL = *(const bf16x8*)&Bl[bc][gq * 8];
        f32x4v t = {0, 0, 0, 0};
        t = __builtin_amdgcn_mfma_f32_16x16x32_bf16(aH, bH, t, 0, 0, 0);
        t = __builtin_amdgcn_mfma_f32_16x16x32_bf16(aL, bH, t, 0, 0, 0);
        t = __builtin_amdgcn_mfma_f32_16x16x32_bf16(aH, bL, t, 0, 0, 0);
        const int gcol = c0 + cf * 16 + rl;
        #pragma unroll
        for (int r = 0; r < 4; ++r) {
            const int grow = row0 + w * 16 + gq * 4 + r;
            if (grow < NN) C[(size_t)grow * 128 + gcol] = __float2half_rn(t[r]);
        }
    }
}

// ================= softmax+aggregate device helpers (proven bodies) =================

__device__ __forceinline__ void softagg1_node(int n, int lane,
                                              const int* __restrict__ rowptr,
                                              const int* __restrict__ psrc,
                                              const float* __restrict__ a_s,
                                              const float* __restrict__ a_d,
                                              const __half* __restrict__ xl,
                                              const float* __restrict__ bias,
                                              float* __restrict__ out) {
    const int r0 = rowptr[n], r1 = rowptr[n + 1];
    const int hh = lane >> 4;
    const float ad = a_d[n * NH + hh];

    const h4* X = (const h4*)xl;   // row stride 64 h4 units (256 halves)
    float4 A0 = {0,0,0,0}, A1 = {0,0,0,0}, A2 = {0,0,0,0}, A3 = {0,0,0,0};
    float sum = 0.f;
    int j = r0;
    for (; j + 7 < r1; j += 8) {
        const int s0 = psrc[j],     s1 = psrc[j + 1], s2 = psrc[j + 2], s3 = psrc[j + 3];
        const int s4 = psrc[j + 4], s5 = psrc[j + 5], s6 = psrc[j + 6], s7 = psrc[j + 7];
        const float w0 = elw(a_s[s0 * NH + hh] + ad);
        const float w1 = elw(a_s[s1 * NH + hh] + ad);
        const float w2 = elw(a_s[s2 * NH + hh] + ad);
        const float w3 = elw(a_s[s3 * NH + hh] + ad);
        const float w4 = elw(a_s[s4 * NH + hh] + ad);
        const float w5 = elw(a_s[s5 * NH + hh] + ad);
        const float w6 = elw(a_s[s6 * NH + hh] + ad);
        const float w7 = elw(a_s[s7 * NH + hh] + ad);
        sum += ((w0 + w1) + (w2 + w3)) + ((w4 + w5) + (w6 + w7));
        const h4 v0 = X[(size_t)s0 * 64 + lane];
        const h4 v1 = X[(size_t)s1 * 64 + lane];
        const h4 v2 = X[(size_t)s2 * 64 + lane];
        const h4 v3 = X[(size_t)s3 * 64 + lane];
        const h4 v4 = X[(size_t)s4 * 64 + lane];
        const h4 v5 = X[(size_t)s5 * 64 + lane];
        const h4 v6 = X[(size_t)s6 * 64 + lane];
        const h4 v7 = X[(size_t)s7 * 64 + lane];
        float2 l0 = __half22float2(v0.a), m0 = __half22float2(v0.b);
        float2 l1 = __half22float2(v1.a), m1 = __half22float2(v1.b);
        float2 l2 = __half22float2(v2.a), m2 = __half22float2(v2.b);
        float2 l3 = __half22float2(v3.a), m3 = __half22float2(v3.b);
        float2 l4 = __half22float2(v4.a), m4 = __half22float2(v4.b);
        float2 l5 = __half22float2(v5.a), m5 = __half22float2(v5.b);
        float2 l6 = __half22float2(v6.a), m6 = __half22float2(v6.b);
        float2 l7 = __half22float2(v7.a), m7 = __half22float2(v7.b);
        A0.x = fmaf(w0, l0.x, A0.x); A0.y = fmaf(w0, l0.y, A0.y);
        A0.z = fmaf(w0, m0.x, A0.z); A0.w = fmaf(w0, m0.y, A0.w);
        A1.x = fmaf(w1, l1.x, A1.x); A1.y = fmaf(w1, l1.y, A1.y);
        A1.z = fmaf(w1, m1.x, A1.z); A1.w = fmaf(w1, m1.y, A1.w);
        A2.x = fmaf(w2, l2.x, A2.x); A2.y = fmaf(w2, l2.y, A2.y);
        A2.z = fmaf(w2, m2.x, A2.z); A2.w = fmaf(w2, m2.y, A2.w);
        A3.x = fmaf(w3, l3.x, A3.x); A3.y = fmaf(w3, l3.y, A3.y);
        A3.z = fmaf(w3, m3.x, A3.z); A3.w = fmaf(w3, m3.y, A3.w);
        A0.x = fmaf(w4, l4.x, A0.x); A0.y = fmaf(w4, l4.y, A0.y);
        A0.z = fmaf(w4, m4.x, A0.z); A0.w = fmaf(w4, m4.y, A0.w);
        A1.x = fmaf(w5, l5.x, A1.x); A1.y = fmaf(w5, l5.y, A1.y);
        A1.z = fmaf(w5, m5.x, A1.z); A1.w = fmaf(w5, m5.y, A1.w);
        A2.x = fmaf(w6, l6.x, A2.x); A2.y = fmaf(w6, l6.y, A2.y);
        A2.z = fmaf(w6, m6.x, A2.z); A2.w = fmaf(w6, m6.y, A2.w);
        A3.x = fmaf(w7, l7.x, A3.x); A3.y = fmaf(w7, l7.y, A3.y);
        A3.z = fmaf(w7, m7.x, A3.z); A3.w = fmaf(w7, m7.y, A3.w);
    }
    for (; j < r1; ++j) {
        const int s0 = psrc[j];
        const float w0 = elw(a_s[s0 * NH + hh] + ad);
        sum += w0;
        const h4 v0 = X[(size_t)s0 * 64 + lane];
        float2 l0 = __half22float2(v0.a), m0 = __half22float2(v0.b);
        A0.x = fmaf(w0, l0.x, A0.x); A0.y = fmaf(w0, l0.y, A0.y);
        A0.z = fmaf(w0, m0.x, A0.z); A0.w = fmaf(w0, m0.y, A0.w);
    }
    const float inv = 1.f / (sum + 1e-30f);
    float4 t;
    t.x = ((A0.x + A1.x) + (A2.x + A3.x)) * inv;
    t.y = ((A0.y + A1.y) + (A2.y + A3.y)) * inv;
    t.z = ((A0.z + A1.z) + (A2.z + A3.z)) * inv;
    t.w = ((A0.w + A1.w) + (A2.w + A3.w)) * inv;
    #pragma unroll
    for (int msk = 16; msk < 64; msk <<= 1) {
        t.x += __shfl_xor(t.x, msk, 64);
        t.y += __shfl_xor(t.y, msk, 64);
        t.z += __shfl_xor(t.z, msk, 64);
        t.w += __shfl_xor(t.w, msk, 64);
    }
    if (lane < 16) {
        const float4 b = ((const float4*)bias)[lane];
        float4 o;
        o.x = t.x * 0.25f + b.x; o.y = t.y * 0.25f + b.y;
        o.z = t.z * 0.25f + b.z; o.w = t.w * 0.25f + b.w;
        ((float4*)out)[(size_t)n * 16 + lane] = o;
    }
}

__device__ __forceinline__ void softagg2_node(int n, int lane,
                                              const int* __restrict__ rowptr,
                                              const int* __restrict__ psrc,
                                              const float* __restrict__ a_s,
                                              const float* __restrict__ a_d,
                                              float* __restrict__ alpha_p,
                                              float* __restrict__ inv_s,
                                              const __half* __restrict__ xl,
                                              const float* __restrict__ bias,
                                              float* __restrict__ out) {
    const int r0 = rowptr[n], r1 = rowptr[n + 1];
    const int cl = lane & 31, half = lane >> 5, hh = cl >> 3;
    const float ad = a_d[n * NH + hh];
    const bool writer = (cl & 7) == 0;   // one lane per (half, head) writes raw w

    const h4* X = (const h4*)xl;   // row stride 32 h4 units (128 halves)
    float4 A0 = {0,0,0,0}, A1 = {0,0,0,0};
    float sum = 0.f;
    int j = r0;
    for (; j + 7 < r1; j += 8) {
        const int ja = j + half, jc = j + 2 + half, je = j + 4 + half, jg = j + 6 + half;
        const int sa = psrc[ja], sc = psrc[jc], se = psrc[je], sg = psrc[jg];
        const float wa = elw(a_s[sa * NH + hh] + ad);
        const float wc = elw(a_s[sc * NH + hh] + ad);
        const float we = elw(a_s[se * NH + hh] + ad);
        const float wg = elw(a_s[sg * NH + hh] + ad);
        if (writer) {
            alpha_p[ja * NH + hh] = wa; alpha_p[jc * NH + hh] = wc;
            alpha_p[je * NH + hh] = we; alpha_p[jg * NH + hh] = wg;
        }
        sum += (wa + wc) + (we + wg);
        const h4 va = X[(size_t)sa * 32 + cl];
        const h4 vc = X[(size_t)sc * 32 + cl];
        const h4 ve = X[(size_t)se * 32 + cl];
        const h4 vg = X[(size_t)sg * 32 + cl];
        const float2 la = __half22float2(va.a), ma = __half22float2(va.b);
        const float2 lc = __half22float2(vc.a), mc = __half22float2(vc.b);
        const float2 le = __half22float2(ve.a), me = __half22float2(ve.b);
        const float2 lg = __half22float2(vg.a), mg = __half22float2(vg.b);
        A0.x = fmaf(wa, la.x, A0.x); A0.y = fmaf(wa, la.y, A0.y);
        A0.z = fmaf(wa, ma.x, A0.z); A0.w = fmaf(wa, ma.y, A0.w);
        A1.x = fmaf(wc, lc.x, A1.x); A1.y = fmaf(wc, lc.y, A1.y);
        A1.z = fmaf(wc, mc.x, A1.z); A1.w = fmaf(wc, mc.y, A1.w);
        A0.x = fmaf(we, le.x, A0.x); A0.y = fmaf(we, le.y, A0.y);
        A0.z = fmaf(we, me.x, A0.z); A0.w = fmaf(we, me.y, A0.w);
        A1.x = fmaf(wg, lg.x, A1.x); A1.y = fmaf(wg, lg.y, A1.y);
        A1.z = fmaf(wg, mg.x, A1.z); A1.w = fmaf(wg, mg.y, A1.w);
    }
    for (; j < r1; j += 2) {
        const int ja = j + half;
        const bool valid = ja < r1;
        const int sa = psrc[valid ? ja : r0];
        float wa = 0.f;
        if (valid) {
            wa = elw(a_s[sa * NH + hh] + ad);
            if (writer) alpha_p[ja * NH + hh] = wa;
        }
        sum += wa;
        const h4 va = X[(size_t)sa * 32 + cl];
        const float2 la = __half22float2(va.a), ma = __half22float2(va.b);
        A0.x = fmaf(wa, la.x, A0.x); A0.y = fmaf(wa, la.y, A0.y);
        A0.z = fmaf(wa, ma.x, A0.z); A0.w = fmaf(wa, ma.y, A0.w);
    }
    // merge halves' partial sums, then normalize
    sum += __shfl_xor(sum, 32, 64);
    const float inv = 1.f / (sum + 1e-30f);
    if (writer && half == 0) inv_s[n * NH + hh] = inv;

    float4 t;
    t.x = A0.x + A1.x; t.y = A0.y + A1.y; t.z = A0.z + A1.z; t.w = A0.w + A1.w;
    t.x += __shfl_xor(t.x, 32, 64);
    t.y += __shfl_xor(t.y, 32, 64);
    t.z += __shfl_xor(t.z, 32, 64);
    t.w += __shfl_xor(t.w, 32, 64);
    t.x *= inv; t.y *= inv; t.z *= inv; t.w *= inv;
    #pragma unroll
    for (int q = 0; q < 2; ++q) {
        const int msk = (q == 0) ? 8 : 16;
        t.x += __shfl_xor(t.x, msk, 64);
        t.y += __shfl_xor(t.y, msk, 64);
        t.z += __shfl_xor(t.z, msk, 64);
        t.w += __shfl_xor(t.w, msk, 64);
    }
    if (lane < 8) {
        const float4 b = ((const float4*)bias)[lane];
        float4 o;
        o.x = t.x * 0.25f + b.x; o.y = t.y * 0.25f + b.y;
        o.z = t.z * 0.25f + b.z; o.w = t.w * 0.25f + b.w;
        ((float4*)out)[(size_t)n * 8 + lane] = o;
    }
}

// ================= kernels =================

__global__ __launch_bounds__(256) void count_deg_k(const int* __restrict__ ei,
                                                   int* __restrict__ deg) {
    const int e = blockIdx.x * 256 + threadIdx.x;
    if (e < EE) atomicAdd(&deg[ei[EE + e]], 1);
}

__global__ __launch_bounds__(256) void pack_w1_k(const float* __restrict__ mW1,
                                                 float* __restrict__ W1pq) {
    const int idx = blockIdx.x * 256 + threadIdx.x;
    if (idx >= 32 * 128) return;
    const int k = idx >> 7, j = idx & 127;
    W1pq[idx] = (j < 64) ? mW1[k * 64 + j] : mW1[(36 + k) * 64 + (j - 64)];
}

// ---- multi-block exclusive scan (3 phases; HW-verified logic) ----
__global__ __launch_bounds__(256) void scan1_k(const int* __restrict__ deg,
                                               int* __restrict__ bsum) {
    __shared__ int sw[4];
    const int tid = threadIdx.x, lane = tid & 63, wv = tid >> 6;
    const int i = blockIdx.x * 256 + tid;
    int s = (i < NN) ? deg[i] : 0;
    #pragma unroll
    for (int d = 1; d < 64; d <<= 1) s += __shfl_xor(s, d, 64);
    if (lane == 0) sw[wv] = s;
    __syncthreads();
    if (tid == 0) bsum[blockIdx.x] = sw[0] + sw[1] + sw[2] + sw[3];
}

__global__ __launch_bounds__(256) void scan2_k(const int* __restrict__ bsum,
                                               int* __restrict__ boff) {
    __shared__ int sw[8];
    const int tid = threadIdx.x, lane = tid & 63, wv = tid >> 6;
    int v = (tid < NCH) ? bsum[tid] : 0;
    int incl = v;
    #pragma unroll
    for (int d = 1; d < 64; d <<= 1) {
        int t = __shfl_up(incl, d, 64);
        if (lane >= d) incl += t;
    }
    if (lane == 63) sw[wv] = incl;
    __syncthreads();
    if (wv == 0 && lane < 4) {
        int s4 = sw[lane];
        #pragma unroll
        for (int d = 1; d < 4; d <<= 1) {
            int t = __shfl_up(s4, d, 64);
            if (lane >= d) s4 += t;
        }
        sw[lane + 4] = s4;
    }
    __syncthreads();
    const int woff = (wv > 0) ? sw[wv - 1 + 4] : 0;
    if (tid < NCH) boff[tid] = woff + incl - v;
}

__global__ __launch_bounds__(256) void scan3_k(const int* __restrict__ deg,
                                               const int* __restrict__ boff,
                                               int* __restrict__ rowptr,
                                               int* __restrict__ cursor) {
    __shared__ int sw[8];
    const int tid = threadIdx.x, lane = tid & 63, wv = tid >> 6;
    const int c = blockIdx.x;
    const int i = c * 256 + tid;
    int v = (i < NN) ? deg[i] : 0;
    int incl = v;
    #pragma unroll
    for (int d = 1; d < 64; d <<= 1) {
        int t = __shfl_up(incl, d, 64);
        if (lane >= d) incl += t;
    }
    if (lane == 63) sw[wv] = incl;
    __syncthreads();
    if (wv == 0 && lane < 4) {
        int s4 = sw[lane];
        #pragma unroll
        for (int d = 1; d < 4; d <<= 1) {
            int t = __shfl_up(s4, d, 64);
            if (lane >= d) s4 += t;
        }
        sw[lane + 4] = s4;
    }
    __syncthreads();
    const int excl = boff[c] + ((wv > 0) ? sw[wv - 1 + 4] : 0) + incl - v;
    if (i < NN) { rowptr[i] = excl; cursor[i] = excl; }
    if (c == 0 && tid == 0) rowptr[NN] = EE;
}

__global__ __launch_bounds__(256) void scatter_perm_k(const int* __restrict__ ei,
                                                      int* __restrict__ cursor,
                                                      int* __restrict__ perm,
                                                      int* __restrict__ psrc,
                                                      int* __restrict__ pdst) {
    const int e = blockIdx.x * 256 + threadIdx.x;
    if (e >= EE) return;
    const int d = ei[EE + e];
    const int p = atomicAdd(&cursor[d], 1);
    perm[p] = e;
    psrc[p] = ei[e];
    pdst[p] = d;
}

__global__ __launch_bounds__(256) void softagg1h_k(const int* __restrict__ rowptr,
                                                   const int* __restrict__ psrc,
                                                   const float* __restrict__ a_s,
                                                   const float* __restrict__ a_d,
                                                   const __half* __restrict__ xl,
                                                   const float* __restrict__ bias,
                                                   float* __restrict__ out) {
    const int n = blockIdx.x * 4 + (threadIdx.x >> 6);
    if (n >= NN) return;
    softagg1_node(n, threadIdx.x & 63, rowptr, psrc, a_s, a_d, xl, bias, out);
}

__global__ __launch_bounds__(256) void softagg2h_k(const int* __restrict__ rowptr,
                                                   const int* __restrict__ psrc,
                                                   const float* __restrict__ a_s,
                                                   const float* __restrict__ a_d,
                                                   float* __restrict__ alpha_p,
                                                   float* __restrict__ inv_s,
                                                   const __half* __restrict__ xl,
                                                   const float* __restrict__ bias,
                                                   float* __restrict__ out) {
    const int n = blockIdx.x * 4 + (threadIdx.x >> 6);
    if (n >= NN) return;
    softagg2_node(n, threadIdx.x & 63, rowptr, psrc, a_s, a_d, alpha_p, inv_s, xl, bias, out);
}

__global__ __launch_bounds__(256) void edge_mlp_k(const __half* __restrict__ PQ,
                                                  const float* __restrict__ alpha_p,
                                                  const float* __restrict__ inv_s,
                                                  const int* __restrict__ psrc,
                                                  const int* __restrict__ pdst,
                                                  const int* __restrict__ perm,
                                                  const float* __restrict__ mW1,
                                                  const float* __restrict__ mb1,
                                                  const float* __restrict__ mW2,
                                                  const float* __restrict__ mb2,
                                                  float* __restrict__ out) {
    const int lane = threadIdx.x & 63, wvv = threadIdx.x >> 6;
    const int g = lane >> 4, c = lane & 15;

    const float4 wa0 = *(const float4*)&mW1[32 * 64 + c * 4];
    const float4 wa1 = *(const float4*)&mW1[33 * 64 + c * 4];
    const float4 wa2 = *(const float4*)&mW1[34 * 64 + c * 4];
    const float4 wa3 = *(const float4*)&mW1[35 * 64 + c * 4];
    const float4 b1v = *(const float4*)&mb1[c * 4];
    const float4 w2a = *(const float4*)&mW2[c * 8];
    const float4 w2b = *(const float4*)&mW2[c * 8 + 4];
    const float bo0 = mb2[0], bo1 = mb2[1];

    const h4* PQ4 = (const h4*)PQ;
    const int gw = blockIdx.x * 4 + wvv;
    const int stride4 = gridDim.x * 4 * 4;

    for (int jb = gw * 4; jb < EE; jb += stride4) {
        const int j = jb + g;
        const int s = psrc[j];
        const int d = pdst[j];
        const float4 ar = *(const float4*)&alpha_p[(size_t)j * 4];
        const float4 iv = *(const float4*)&inv_s[(size_t)d * 4];
        const float al0 = ar.x * iv.x, al1 = ar.y * iv.y;
        const float al2 = ar.z * iv.z, al3 = ar.w * iv.w;
        const h4 ph = PQ4[(size_t)s * 32 + c];
        const h4 qh = PQ4[(size_t)d * 32 + 16 + c];
        const float2 pl = __half22float2(ph.a), pm = __half22float2(ph.b);
        const float2 ql = __half22float2(qh.a), qm = __half22float2(qh.b);
        float4 h;
        h.x = pl.x + ql.x + b1v.x; h.y = pl.y + ql.y + b1v.y;
        h.z = pm.x + qm.x + b1v.z; h.w = pm.y + qm.y + b1v.w;
        h.x = fmaf(al0, wa0.x, h.x); h.y = fmaf(al0, wa0.y, h.y);
        h.z = fmaf(al0, wa0.z, h.z); h.w = fmaf(al0, wa0.w, h.w);
        h.x = fmaf(al1, wa1.x, h.x); h.y = fmaf(al1, wa1.y, h.y);
        h.z = fmaf(al1, wa1.z, h.z); h.w = fmaf(al1, wa1.w, h.w);
        h.x = fmaf(al2, wa2.x, h.x); h.y = fmaf(al2, wa2.y, h.y);
        h.z = fmaf(al2, wa2.z, h.z); h.w = fmaf(al2, wa2.w, h.w);
        h.x = fmaf(al3, wa3.x, h.x); h.y = fmaf(al3, wa3.y, h.y);
        h.z = fmaf(al3, wa3.z, h.z); h.w = fmaf(al3, wa3.w, h.w);
        h.x = fmaxf(h.x, 0.f); h.y = fmaxf(h.y, 0.f);
        h.z = fmaxf(h.z, 0.f); h.w = fmaxf(h.w, 0.f);

        float v0 = h.x * w2a.x + h.y * w2a.z + h.z * w2b.x + h.w * w2b.z;
        float v1 = h.x * w2a.y + h.y * w2a.w + h.z * w2b.y + h.w * w2b.w;
        #pragma unroll
        for (int msk = 1; msk < 16; msk <<= 1) {
            v0 += __shfl_xor(v0, msk, 64);
            v1 += __shfl_xor(v1, msk, 64);
        }
        if (c == 0)
            *(float2*)&out[(size_t)perm[j] * 2] = make_float2(v0 + bo0, v1 + bo1);
    }
}

extern "C" void kernel_launch(void* const* d_in, const int* in_sizes, int n_in,
                              void* d_out, int out_size, void* d_ws, size_t ws_size,
                              hipStream_t stream) {
    const float* x        = (const float*)d_in[0];
    const int*   ei       = (const int*)d_in[1];
    // d_in[2] edge_attr: unused (edge_dim=None). d_in[3] flag: unused.
    const float* W1       = (const float*)d_in[4];
    const float* att1_src = (const float*)d_in[5];
    const float* att1_dst = (const float*)d_in[6];
    const float* b1       = (const float*)d_in[7];
    const float* W3       = (const float*)d_in[8];
    const float* att3_src = (const float*)d_in[9];
    const float* att3_dst = (const float*)d_in[10];
    const float* b3       = (const float*)d_in[11];
    const float* mW1      = (const float*)d_in[12];
    const float* mb1      = (const float*)d_in[13];
    const float* mW2      = (const float*)d_in[14];
    const float* mb2      = (const float*)d_in[15];

    float* out_nodes = (float*)d_out;               // [N,32]
    float* out_edges = out_nodes + (size_t)NN * 32; // [E,2]

    // workspace layout (floats/ints)
    float* ws = (float*)d_ws;
    __half*   xlh     = (__half*)ws;                  // N*256 halves (layer-1 GEMM out)
    __half*   xl2h    = (__half*)ws;                  // N*128 halves (layer-2 GEMM out)
    __half*   PQh     = (__half*)ws;                  // N*128 halves, after xl2h dead
    float*    h1      = ws + 12800000;                // N*64
    float*    alpha_p = ws + 16000000;                // E*4 (CSR-order raw w, layer 2)
    float*    a_s     = ws + 25600000;                // N*4
    float*    a_d     = ws + 25800000;                // N*4
    float*    W1pq    = ws + 26000000;                // 32*128
    float*    inv_s   = ws + 26100000;                // N*4
    int*      bsum    = (int*)(ws + 26300000);        // NCH
    int*      boff    = (int*)(ws + 26301000);        // NCH
    int*      deg     = (int*)(ws + 26400000);        // N
    int*      cursor  = (int*)(ws + 26450000);        // N
    int*      rowptr  = (int*)(ws + 26500000);        // N+1
    int*      perm    = (int*)(ws + 26550008);        // E
    int*      psrc    = (int*)(ws + 27350008);        // E
    int*      pdst    = (int*)(ws + 28150008);        // E

    const int NB4 = (NN + 3) / 4;

    // 1) CSR build front half
    hipMemsetAsync(deg, 0, (size_t)NN * 4, stream);
    count_deg_k<<<EB, 256, 0, stream>>>(ei, deg);
    pack_w1_k<<<16, 256, 0, stream>>>(mW1, W1pq);
    // 2) layer-1 GEMM on matrix cores (split-bf16, fp32-grade)
    gemm1_mfma_k<<<dim3(GR64, 4), 256, 0, stream>>>(x, W1, xlh, att1_src, att1_dst,
                                                    a_s, a_d);
    // 3) multi-block exclusive scan -> rowptr/cursor
    scan1_k<<<NCH, 256, 0, stream>>>(deg, bsum);
    scan2_k<<<1, 256, 0, stream>>>(bsum, boff);
    scan3_k<<<NCH, 256, 0, stream>>>(deg, boff, rowptr, cursor);
    // 4) scatter edges into CSR order
    scatter_perm_k<<<EB, 256, 0, stream>>>(ei, cursor, perm, psrc, pdst);
    // 5) layer-1 softmax+aggregate
    softagg1h_k<<<NB4, 256, 0, stream>>>(rowptr, psrc, a_s, a_d, xlh, b1, h1);
    // 6) layer-2 GEMM on matrix cores (split-bf16)
    gemm2_mfma_k<<<dim3(GR64, 2), 256, 0, stream>>>(h1, W3, xl2h, att3_src, att3_dst,
                                                    a_s, a_d);
    // 7) layer-2 softmax+aggregate
    softagg2h_k<<<NB4, 256, 0, stream>>>(rowptr, psrc, a_s, a_d, alpha_p, inv_s, xl2h, b3,
                                         out_nodes);
    // 8) PQ GEMM on matrix cores (K=32; xl2h dead -> PQh aliases it)
    gemmpq_mfma_k<<<dim3(GR64, 2), 256, 0, stream>>>(out_nodes, W1pq, PQh);
    // 9) edge MLP
    edge_mlp_k<<<2048, 256, 0, stream>>>(PQh, alpha_p, inv_s, psrc, pdst, perm,
                                         mW1, mb1, mW2, mb2, out_edges);
}

// Round 12
// 405.465 us; speedup vs baseline: 1.1099x; 1.0278x over previous
//
#include <hip/hip_runtime.h>
#include <hip/hip_fp16.h>

// Problem constants
constexpr int NN   = 50000;
constexpr int EE   = 800000;
constexpr int INF  = 128;   // input feat
constexpr int NH   = 4;     // heads
constexpr int GR64 = (NN + 63) / 64;        // 782 row tiles
constexpr int EB   = (EE + 255) / 256;      // 3125 edge blocks
constexpr int NCH  = (NN + 255) / 256;      // 196 scan chunks

struct __align__(8) h4 { __half2 a, b; };   // 4 halves = 8 bytes

typedef short bf16x8 __attribute__((ext_vector_type(8)));
typedef float f32x4v __attribute__((ext_vector_type(4)));

__device__ __forceinline__ float elw(float a) {
    a = (a > 0.f) ? a : 0.2f * a;          // leaky_relu(0.2)
    return __expf(a);                       // exp without max-sub (scores bounded)
}

__device__ __forceinline__ short bf16_hi(float x) {
    return (short)(__float_as_uint(x) >> 16);   // truncate to bf16
}
__device__ __forceinline__ float bf16_back(short h) {
    return __uint_as_float(((unsigned)(unsigned short)h) << 16);
}

// ======== FUSED: count_deg (even blocks) || layer-1 MFMA GEMM (odd blocks) ========
// Round-robin role mapping (NOT block-ordered like R6) so the atomic-latency-bound
// counting co-resides with and hides under the MFMA GEMM.
__global__ __launch_bounds__(256) void cnt_gemm1_k(const int* __restrict__ ei,
                                                   int* __restrict__ deg,
                                                   const float* __restrict__ A,   // x [N][128]
                                                   const float* __restrict__ B,   // W1 [128][256]
                                                   __half* __restrict__ C,        // xlh [N][256]
                                                   const float* __restrict__ att_s,
                                                   const float* __restrict__ att_d,
                                                   float* __restrict__ a_s,
                                                   float* __restrict__ a_d) {
    __shared__ short Ah[64][72], Al[64][72];
    __shared__ short Bh[64][72], Bl[64][72];   // transposed: [col][k_local]
    const int b = blockIdx.x;
    const int tid = threadIdx.x;

    if ((b & 1) == 0) {                        // ---- count_deg role ----
        const int eb = b >> 1;
        if (eb < EB) {
            const int e = eb * 256 + tid;
            if (e < EE) atomicAdd(&deg[ei[EE + e]], 1);
        }
        return;
    }

    // ---- gemm1 role: tile t in [0, GR64*4) ----
    const int t    = b >> 1;
    const int lane = tid & 63, w = tid >> 6;
    const int row0 = (t % GR64) * 64;
    const int head = t / GR64;                 // 64 cols per head
    const int c0   = head * 64;
    const int rl = lane & 15, gq = lane >> 4;

    f32x4v acc0 = {0,0,0,0}, acc1 = {0,0,0,0}, acc2 = {0,0,0,0}, acc3 = {0,0,0,0};

    for (int ks = 0; ks < 2; ++ks) {
        {
            const int ar = tid >> 2;               // 0..63
            const int kb = (tid & 3) * 4;          // 0,4,8,12
            const int grow = row0 + ar;
            #pragma unroll
            for (int pass = 0; pass < 4; ++pass) {
                const int kl = kb + pass * 16;     // 0..63
                float4 v = make_float4(0.f, 0.f, 0.f, 0.f);
                if (grow < NN) v = *(const float4*)(A + (size_t)grow * 128 + ks * 64 + kl);
                short4 hi, lo;
                hi.x = bf16_hi(v.x); lo.x = bf16_hi(v.x - bf16_back(hi.x));
                hi.y = bf16_hi(v.y); lo.y = bf16_hi(v.y - bf16_back(hi.y));
                hi.z = bf16_hi(v.z); lo.z = bf16_hi(v.z - bf16_back(hi.z));
                hi.w = bf16_hi(v.w); lo.w = bf16_hi(v.w - bf16_back(hi.w));
                *(short4*)&Ah[ar][kl] = hi;
                *(short4*)&Al[ar][kl] = lo;
            }
        }
        {
            const int c  = lane;                   // 0..63
            const int kb = w * 16;                 // 16 k per wave
            #pragma unroll
            for (int chunk = 0; chunk < 2; ++chunk) {
                short hi8[8], lo8[8];
                #pragma unroll
                for (int i = 0; i < 8; ++i) {
                    const int kl = kb + chunk * 8 + i;
                    const float v = B[(size_t)(ks * 64 + kl) * 256 + c0 + c];
                    hi8[i] = bf16_hi(v);
                    lo8[i] = bf16_hi(v - bf16_back(hi8[i]));
                }
                *(bf16x8*)&Bh[c][kb + chunk * 8] =
                    (bf16x8){hi8[0],hi8[1],hi8[2],hi8[3],hi8[4],hi8[5],hi8[6],hi8[7]};
                *(bf16x8*)&Bl[c][kb + chunk * 8] =
                    (bf16x8){lo8[0],lo8[1],lo8[2],lo8[3],lo8[4],lo8[5],lo8[6],lo8[7]};
            }
        }
        __syncthreads();

        bf16x8 aH0 = *(const bf16x8*)&Ah[w * 16 + rl][gq * 8];
        bf16x8 aH1 = *(const bf16x8*)&Ah[w * 16 + rl][32 + gq * 8];
        bf16x8 aL0 = *(const bf16x8*)&Al[w * 16 + rl][gq * 8];
        bf16x8 aL1 = *(const bf16x8*)&Al[w * 16 + rl][32 + gq * 8];

        #pragma unroll
        for (int cf = 0; cf < 4; ++cf) {
            const int bc = cf * 16 + rl;
            bf16x8 bH0 = *(const bf16x8*)&Bh[bc][gq * 8];
            bf16x8 bH1 = *(const bf16x8*)&Bh[bc][32 + gq * 8];
            bf16x8 bL0 = *(const bf16x8*)&Bl[bc][gq * 8];
            bf16x8 bL1 = *(const bf16x8*)&Bl[bc][32 + gq * 8];
            f32x4v tacc = (cf == 0) ? acc0 : (cf == 1) ? acc1 : (cf == 2) ? acc2 : acc3;
            tacc = __builtin_amdgcn_mfma_f32_16x16x32_bf16(aH0, bH0, tacc, 0, 0, 0);
            tacc = __builtin_amdgcn_mfma_f32_16x16x32_bf16(aL0, bH0, tacc, 0, 0, 0);
            tacc = __builtin_amdgcn_mfma_f32_16x16x32_bf16(aH0, bL0, tacc, 0, 0, 0);
            tacc = __builtin_amdgcn_mfma_f32_16x16x32_bf16(aH1, bH1, tacc, 0, 0, 0);
            tacc = __builtin_amdgcn_mfma_f32_16x16x32_bf16(aL1, bH1, tacc, 0, 0, 0);
            tacc = __builtin_amdgcn_mfma_f32_16x16x32_bf16(aH1, bL1, tacc, 0, 0, 0);
            if (cf == 0) acc0 = tacc; else if (cf == 1) acc1 = tacc;
            else if (cf == 2) acc2 = tacc; else acc3 = tacc;
        }
        __syncthreads();
    }

    float sS[4] = {0.f, 0.f, 0.f, 0.f};
    float sD[4] = {0.f, 0.f, 0.f, 0.f};
    #pragma unroll
    for (int cf = 0; cf < 4; ++cf) {
        const f32x4v tacc = (cf == 0) ? acc0 : (cf == 1) ? acc1 : (cf == 2) ? acc2 : acc3;
        const int gcol = c0 + cf * 16 + rl;
        const float atS = att_s[gcol];
        const float atD = att_d[gcol];
        #pragma unroll
        for (int r = 0; r < 4; ++r) {
            const int grow = row0 + w * 16 + gq * 4 + r;
            if (grow < NN) C[(size_t)grow * 256 + gcol] = __float2half_rn(tacc[r]);
            sS[r] = fmaf(tacc[r], atS, sS[r]);
            sD[r] = fmaf(tacc[r], atD, sD[r]);
        }
    }
    #pragma unroll
    for (int r = 0; r < 4; ++r) {
        #pragma unroll
        for (int msk = 1; msk < 16; msk <<= 1) {
            sS[r] += __shfl_xor(sS[r], msk, 64);
            sD[r] += __shfl_xor(sD[r], msk, 64);
        }
    }
    if (rl == 0) {
        #pragma unroll
        for (int r = 0; r < 4; ++r) {
            const int grow = row0 + w * 16 + gq * 4 + r;
            if (grow < NN) {
                a_s[grow * NH + head] = sS[r];
                a_d[grow * NH + head] = sD[r];
            }
        }
    }
}

// ======== Layer-2 GEMM on MATRIX CORES: [N,64]x[64,128], CH=32 (R11-proven) ========
__global__ __launch_bounds__(256) void gemm2_mfma_k(const float* __restrict__ A,   // h1 [N][64]
                                                    const float* __restrict__ B,   // W3 [64][128]
                                                    __half* __restrict__ C,        // xl2h [N][128]
                                                    const float* __restrict__ att_s,
                                                    const float* __restrict__ att_d,
                                                    float* __restrict__ a_s,
                                                    float* __restrict__ a_d) {
    __shared__ short Ah[64][72], Al[64][72];
    __shared__ short Bh[64][72], Bl[64][72];   // transposed: [col][k]
    const int tid  = threadIdx.x;
    const int lane = tid & 63, w = tid >> 6;
    const int row0 = blockIdx.x * 64;
    const int c0   = blockIdx.y * 64;          // cols c0..c0+63 -> heads c0/32, c0/32+1
    const int rl = lane & 15, gq = lane >> 4;

    {
        const int ar = tid >> 2;
        const int kb = (tid & 3) * 4;
        const int grow = row0 + ar;
        #pragma unroll
        for (int pass = 0; pass < 4; ++pass) {
            const int kl = kb + pass * 16;
            float4 v = make_float4(0.f, 0.f, 0.f, 0.f);
            if (grow < NN) v = *(const float4*)(A + (size_t)grow * 64 + kl);
            short4 hi, lo;
            hi.x = bf16_hi(v.x); lo.x = bf16_hi(v.x - bf16_back(hi.x));
            hi.y = bf16_hi(v.y); lo.y = bf16_hi(v.y - bf16_back(hi.y));
            hi.z = bf16_hi(v.z); lo.z = bf16_hi(v.z - bf16_back(hi.z));
            hi.w = bf16_hi(v.w); lo.w = bf16_hi(v.w - bf16_back(hi.w));
            *(short4*)&Ah[ar][kl] = hi;
            *(short4*)&Al[ar][kl] = lo;
        }
    }
    {
        const int c  = lane;
        const int kb = w * 16;
        #pragma unroll
        for (int chunk = 0; chunk < 2; ++chunk) {
            short hi8[8], lo8[8];
            #pragma unroll
            for (int i = 0; i < 8; ++i) {
                const int kl = kb + chunk * 8 + i;
                const float v = B[(size_t)kl * 128 + c0 + c];
                hi8[i] = bf16_hi(v);
                lo8[i] = bf16_hi(v - bf16_back(hi8[i]));
            }
            *(bf16x8*)&Bh[c][kb + chunk * 8] =
                (bf16x8){hi8[0],hi8[1],hi8[2],hi8[3],hi8[4],hi8[5],hi8[6],hi8[7]};
            *(bf16x8*)&Bl[c][kb + chunk * 8] =
                (bf16x8){lo8[0],lo8[1],lo8[2],lo8[3],lo8[4],lo8[5],lo8[6],lo8[7]};
        }
    }
    __syncthreads();

    bf16x8 aH0 = *(const bf16x8*)&Ah[w * 16 + rl][gq * 8];
    bf16x8 aH1 = *(const bf16x8*)&Ah[w * 16 + rl][32 + gq * 8];
    bf16x8 aL0 = *(const bf16x8*)&Al[w * 16 + rl][gq * 8];
    bf16x8 aL1 = *(const bf16x8*)&Al[w * 16 + rl][32 + gq * 8];

    f32x4v acc0 = {0,0,0,0}, acc1 = {0,0,0,0}, acc2 = {0,0,0,0}, acc3 = {0,0,0,0};
    #pragma unroll
    for (int cf = 0; cf < 4; ++cf) {
        const int bc = cf * 16 + rl;
        bf16x8 bH0 = *(const bf16x8*)&Bh[bc][gq * 8];
        bf16x8 bH1 = *(const bf16x8*)&Bh[bc][32 + gq * 8];
        bf16x8 bL0 = *(const bf16x8*)&Bl[bc][gq * 8];
        bf16x8 bL1 = *(const bf16x8*)&Bl[bc][32 + gq * 8];
        f32x4v t = (cf == 0) ? acc0 : (cf == 1) ? acc1 : (cf == 2) ? acc2 : acc3;
        t = __builtin_amdgcn_mfma_f32_16x16x32_bf16(aH0, bH0, t, 0, 0, 0);
        t = __builtin_amdgcn_mfma_f32_16x16x32_bf16(aL0, bH0, t, 0, 0, 0);
        t = __builtin_amdgcn_mfma_f32_16x16x32_bf16(aH0, bL0, t, 0, 0, 0);
        t = __builtin_amdgcn_mfma_f32_16x16x32_bf16(aH1, bH1, t, 0, 0, 0);
        t = __builtin_amdgcn_mfma_f32_16x16x32_bf16(aL1, bH1, t, 0, 0, 0);
        t = __builtin_amdgcn_mfma_f32_16x16x32_bf16(aH1, bL1, t, 0, 0, 0);
        if (cf == 0) acc0 = t; else if (cf == 1) acc1 = t;
        else if (cf == 2) acc2 = t; else acc3 = t;
    }

    const int h0 = c0 >> 5, h1 = h0 + 1;
    float sS0[4] = {0,0,0,0}, sD0[4] = {0,0,0,0};
    float sS1[4] = {0,0,0,0}, sD1[4] = {0,0,0,0};
    #pragma unroll
    for (int cf = 0; cf < 4; ++cf) {
        const f32x4v t = (cf == 0) ? acc0 : (cf == 1) ? acc1 : (cf == 2) ? acc2 : acc3;
        const int gcol = c0 + cf * 16 + rl;
        const float atS = att_s[gcol];
        const float atD = att_d[gcol];
        #pragma unroll
        for (int r = 0; r < 4; ++r) {
            const int grow = row0 + w * 16 + gq * 4 + r;
            if (grow < NN) C[(size_t)grow * 128 + gcol] = __float2half_rn(t[r]);
            if (cf < 2) { sS0[r] = fmaf(t[r], atS, sS0[r]); sD0[r] = fmaf(t[r], atD, sD0[r]); }
            else        { sS1[r] = fmaf(t[r], atS, sS1[r]); sD1[r] = fmaf(t[r], atD, sD1[r]); }
        }
    }
    #pragma unroll
    for (int r = 0; r < 4; ++r) {
        #pragma unroll
        for (int msk = 1; msk < 16; msk <<= 1) {
            sS0[r] += __shfl_xor(sS0[r], msk, 64);
            sD0[r] += __shfl_xor(sD0[r], msk, 64);
            sS1[r] += __shfl_xor(sS1[r], msk, 64);
            sD1[r] += __shfl_xor(sD1[r], msk, 64);
        }
    }
    if (rl == 0) {
        #pragma unroll
        for (int r = 0; r < 4; ++r) {
            const int grow = row0 + w * 16 + gq * 4 + r;
            if (grow < NN) {
                a_s[grow * NH + h0] = sS0[r];
                a_d[grow * NH + h0] = sD0[r];
                a_s[grow * NH + h1] = sS1[r];
                a_d[grow * NH + h1] = sD1[r];
            }
        }
    }
}

// ======== PQ GEMM on MATRIX CORES: [N,32]x[32,128], K=32 (R11-proven) ========
__global__ __launch_bounds__(256) void gemmpq_mfma_k(const float* __restrict__ A,   // out_nodes [N][32]
                                                     const float* __restrict__ B,   // W1pq [32][128]
                                                     __half* __restrict__ C) {      // PQh [N][128]
    __shared__ short Ah[64][40], Al[64][40];
    __shared__ short Bh[64][40], Bl[64][40];   // transposed: [col][k]
    const int tid  = threadIdx.x;
    const int lane = tid & 63, w = tid >> 6;
    const int row0 = blockIdx.x * 64;
    const int c0   = blockIdx.y * 64;
    const int rl = lane & 15, gq = lane >> 4;

    {
        const int ar = tid >> 2;
        const int kb = (tid & 3) * 4;
        const int grow = row0 + ar;
        #pragma unroll
        for (int pass = 0; pass < 2; ++pass) {
            const int kl = kb + pass * 16;     // 0..31
            float4 v = make_float4(0.f, 0.f, 0.f, 0.f);
            if (grow < NN) v = *(const float4*)(A + (size_t)grow * 32 + kl);
            short4 hi, lo;
            hi.x = bf16_hi(v.x); lo.x = bf16_hi(v.x - bf16_back(hi.x));
            hi.y = bf16_hi(v.y); lo.y = bf16_hi(v.y - bf16_back(hi.y));
            hi.z = bf16_hi(v.z); lo.z = bf16_hi(v.z - bf16_back(hi.z));
            hi.w = bf16_hi(v.w); lo.w = bf16_hi(v.w - bf16_back(hi.w));
            *(short4*)&Ah[ar][kl] = hi;
            *(short4*)&Al[ar][kl] = lo;
        }
    }
    {
        const int c = lane;
        short hi8[8], lo8[8];
        #pragma unroll
        for (int i = 0; i < 8; ++i) {
            const int kl = w * 8 + i;
            const float v = B[(size_t)kl * 128 + c0 + c];
            hi8[i] = bf16_hi(v);
            lo8[i] = bf16_hi(v - bf16_back(hi8[i]));
        }
        *(bf16x8*)&Bh[c][w * 8] =
            (bf16x8){hi8[0],hi8[1],hi8[2],hi8[3],hi8[4],hi8[5],hi8[6],hi8[7]};
        *(bf16x8*)&Bl[c][w * 8] =
            (bf16x8){lo8[0],lo8[1],lo8[2],lo8[3],lo8[4],lo8[5],lo8[6],lo8[7]};
    }
    __syncthreads();

    bf16x8 aH = *(const bf16x8*)&Ah[w * 16 + rl][gq * 8];
    bf16x8 aL = *(const bf16x8*)&Al[w * 16 + rl][gq * 8];

    #pragma unroll
    for (int cf = 0; cf < 4; ++cf) {
        const int bc = cf * 16 + rl;
        bf16x8 bH = *(const bf16x8*)&Bh[bc][gq * 8];
        bf16x8 bL = *(const bf16x8*)&Bl[bc][gq * 8];
        f32x4v t = {0, 0, 0, 0};
        t = __builtin_amdgcn_mfma_f32_16x16x32_bf16(aH, bH, t, 0, 0, 0);
        t = __builtin_amdgcn_mfma_f32_16x16x32_bf16(aL, bH, t, 0, 0, 0);
        t = __builtin_amdgcn_mfma_f32_16x16x32_bf16(aH, bL, t, 0, 0, 0);
        const int gcol = c0 + cf * 16 + rl;
        #pragma unroll
        for (int r = 0; r < 4; ++r) {
            const int grow = row0 + w * 16 + gq * 4 + r;
            if (grow < NN) C[(size_t)grow * 128 + gcol] = __float2half_rn(t[r]);
        }
    }
}

// ================= softmax+aggregate device helpers (psd = packed {src,dst}) =========

__device__ __forceinline__ void softagg1_node(int n, int lane,
                                              const int* __restrict__ rowptr,
                                              const int2* __restrict__ psd,
                                              const float* __restrict__ a_s,
                                              const float* __restrict__ a_d,
                                              const __half* __restrict__ xl,
                                              const float* __restrict__ bias,
                                              float* __restrict__ out) {
    const int r0 = rowptr[n], r1 = rowptr[n + 1];
    const int hh = lane >> 4;
    const float ad = a_d[n * NH + hh];

    const h4* X = (const h4*)xl;   // row stride 64 h4 units (256 halves)
    float4 A0 = {0,0,0,0}, A1 = {0,0,0,0}, A2 = {0,0,0,0}, A3 = {0,0,0,0};
    float sum = 0.f;
    int j = r0;
    for (; j + 7 < r1; j += 8) {
        const int s0 = psd[j].x,     s1 = psd[j + 1].x, s2 = psd[j + 2].x, s3 = psd[j + 3].x;
        const int s4 = psd[j + 4].x, s5 = psd[j + 5].x, s6 = psd[j + 6].x, s7 = psd[j + 7].x;
        const float w0 = elw(a_s[s0 * NH + hh] + ad);
        const float w1 = elw(a_s[s1 * NH + hh] + ad);
        const float w2 = elw(a_s[s2 * NH + hh] + ad);
        const float w3 = elw(a_s[s3 * NH + hh] + ad);
        const float w4 = elw(a_s[s4 * NH + hh] + ad);
        const float w5 = elw(a_s[s5 * NH + hh] + ad);
        const float w6 = elw(a_s[s6 * NH + hh] + ad);
        const float w7 = elw(a_s[s7 * NH + hh] + ad);
        sum += ((w0 + w1) + (w2 + w3)) + ((w4 + w5) + (w6 + w7));
        const h4 v0 = X[(size_t)s0 * 64 + lane];
        const h4 v1 = X[(size_t)s1 * 64 + lane];
        const h4 v2 = X[(size_t)s2 * 64 + lane];
        const h4 v3 = X[(size_t)s3 * 64 + lane];
        const h4 v4 = X[(size_t)s4 * 64 + lane];
        const h4 v5 = X[(size_t)s5 * 64 + lane];
        const h4 v6 = X[(size_t)s6 * 64 + lane];
        const h4 v7 = X[(size_t)s7 * 64 + lane];
        float2 l0 = __half22float2(v0.a), m0 = __half22float2(v0.b);
        float2 l1 = __half22float2(v1.a), m1 = __half22float2(v1.b);
        float2 l2 = __half22float2(v2.a), m2 = __half22float2(v2.b);
        float2 l3 = __half22float2(v3.a), m3 = __half22float2(v3.b);
        float2 l4 = __half22float2(v4.a), m4 = __half22float2(v4.b);
        float2 l5 = __half22float2(v5.a), m5 = __half22float2(v5.b);
        float2 l6 = __half22float2(v6.a), m6 = __half22float2(v6.b);
        float2 l7 = __half22float2(v7.a), m7 = __half22float2(v7.b);
        A0.x = fmaf(w0, l0.x, A0.x); A0.y = fmaf(w0, l0.y, A0.y);
        A0.z = fmaf(w0, m0.x, A0.z); A0.w = fmaf(w0, m0.y, A0.w);
        A1.x = fmaf(w1, l1.x, A1.x); A1.y = fmaf(w1, l1.y, A1.y);
        A1.z = fmaf(w1, m1.x, A1.z); A1.w = fmaf(w1, m1.y, A1.w);
        A2.x = fmaf(w2, l2.x, A2.x); A2.y = fmaf(w2, l2.y, A2.y);
        A2.z = fmaf(w2, m2.x, A2.z); A2.w = fmaf(w2, m2.y, A2.w);
        A3.x = fmaf(w3, l3.x, A3.x); A3.y = fmaf(w3, l3.y, A3.y);
        A3.z = fmaf(w3, m3.x, A3.z); A3.w = fmaf(w3, m3.y, A3.w);
        A0.x = fmaf(w4, l4.x, A0.x); A0.y = fmaf(w4, l4.y, A0.y);
        A0.z = fmaf(w4, m4.x, A0.z); A0.w = fmaf(w4, m4.y, A0.w);
        A1.x = fmaf(w5, l5.x, A1.x); A1.y = fmaf(w5, l5.y, A1.y);
        A1.z = fmaf(w5, m5.x, A1.z); A1.w = fmaf(w5, m5.y, A1.w);
        A2.x = fmaf(w6, l6.x, A2.x); A2.y = fmaf(w6, l6.y, A2.y);
        A2.z = fmaf(w6, m6.x, A2.z); A2.w = fmaf(w6, m6.y, A2.w);
        A3.x = fmaf(w7, l7.x, A3.x); A3.y = fmaf(w7, l7.y, A3.y);
        A3.z = fmaf(w7, m7.x, A3.z); A3.w = fmaf(w7, m7.y, A3.w);
    }
    for (; j < r1; ++j) {
        const int s0 = psd[j].x;
        const float w0 = elw(a_s[s0 * NH + hh] + ad);
        sum += w0;
        const h4 v0 = X[(size_t)s0 * 64 + lane];
        float2 l0 = __half22float2(v0.a), m0 = __half22float2(v0.b);
        A0.x = fmaf(w0, l0.x, A0.x); A0.y = fmaf(w0, l0.y, A0.y);
        A0.z = fmaf(w0, m0.x, A0.z); A0.w = fmaf(w0, m0.y, A0.w);
    }
    const float inv = 1.f / (sum + 1e-30f);
    float4 t;
    t.x = ((A0.x + A1.x) + (A2.x + A3.x)) * inv;
    t.y = ((A0.y + A1.y) + (A2.y + A3.y)) * inv;
    t.z = ((A0.z + A1.z) + (A2.z + A3.z)) * inv;
    t.w = ((A0.w + A1.w) + (A2.w + A3.w)) * inv;
    #pragma unroll
    for (int msk = 16; msk < 64; msk <<= 1) {
        t.x += __shfl_xor(t.x, msk, 64);
        t.y += __shfl_xor(t.y, msk, 64);
        t.z += __shfl_xor(t.z, msk, 64);
        t.w += __shfl_xor(t.w, msk, 64);
    }
    if (lane < 16) {
        const float4 b = ((const float4*)bias)[lane];
        float4 o;
        o.x = t.x * 0.25f + b.x; o.y = t.y * 0.25f + b.y;
        o.z = t.z * 0.25f + b.z; o.w = t.w * 0.25f + b.w;
        ((float4*)out)[(size_t)n * 16 + lane] = o;
    }
}

__device__ __forceinline__ void softagg2_node(int n, int lane,
                                              const int* __restrict__ rowptr,
                                              const int2* __restrict__ psd,
                                              const float* __restrict__ a_s,
                                              const float* __restrict__ a_d,
                                              float* __restrict__ alpha_p,
                                              float* __restrict__ inv_s,
                                              const __half* __restrict__ xl,
                                              const float* __restrict__ bias,
                                              float* __restrict__ out) {
    const int r0 = rowptr[n], r1 = rowptr[n + 1];
    const int cl = lane & 31, half = lane >> 5, hh = cl >> 3;
    const float ad = a_d[n * NH + hh];
    const bool writer = (cl & 7) == 0;   // one lane per (half, head) writes raw w

    const h4* X = (const h4*)xl;   // row stride 32 h4 units (128 halves)
    float4 A0 = {0,0,0,0}, A1 = {0,0,0,0};
    float sum = 0.f;
    int j = r0;
    for (; j + 7 < r1; j += 8) {
        const int ja = j + half, jc = j + 2 + half, je = j + 4 + half, jg = j + 6 + half;
        const int sa = psd[ja].x, sc = psd[jc].x, se = psd[je].x, sg = psd[jg].x;
        const float wa = elw(a_s[sa * NH + hh] + ad);
        const float wc = elw(a_s[sc * NH + hh] + ad);
        const float we = elw(a_s[se * NH + hh] + ad);
        const float wg = elw(a_s[sg * NH + hh] + ad);
        if (writer) {
            alpha_p[ja * NH + hh] = wa; alpha_p[jc * NH + hh] = wc;
            alpha_p[je * NH + hh] = we; alpha_p[jg * NH + hh] = wg;
        }
        sum += (wa + wc) + (we + wg);
        const h4 va = X[(size_t)sa * 32 + cl];
        const h4 vc = X[(size_t)sc * 32 + cl];
        const h4 ve = X[(size_t)se * 32 + cl];
        const h4 vg = X[(size_t)sg * 32 + cl];
        const float2 la = __half22float2(va.a), ma = __half22float2(va.b);
        const float2 lc = __half22float2(vc.a), mc = __half22float2(vc.b);
        const float2 le = __half22float2(ve.a), me = __half22float2(ve.b);
        const float2 lg = __half22float2(vg.a), mg = __half22float2(vg.b);
        A0.x = fmaf(wa, la.x, A0.x); A0.y = fmaf(wa, la.y, A0.y);
        A0.z = fmaf(wa, ma.x, A0.z); A0.w = fmaf(wa, ma.y, A0.w);
        A1.x = fmaf(wc, lc.x, A1.x); A1.y = fmaf(wc, lc.y, A1.y);
        A1.z = fmaf(wc, mc.x, A1.z); A1.w = fmaf(wc, mc.y, A1.w);
        A0.x = fmaf(we, le.x, A0.x); A0.y = fmaf(we, le.y, A0.y);
        A0.z = fmaf(we, me.x, A0.z); A0.w = fmaf(we, me.y, A0.w);
        A1.x = fmaf(wg, lg.x, A1.x); A1.y = fmaf(wg, lg.y, A1.y);
        A1.z = fmaf(wg, mg.x, A1.z); A1.w = fmaf(wg, mg.y, A1.w);
    }
    for (; j < r1; j += 2) {
        const int ja = j + half;
        const bool valid = ja < r1;
        const int sa = psd[valid ? ja : r0].x;
        float wa = 0.f;
        if (valid) {
            wa = elw(a_s[sa * NH + hh] + ad);
            if (writer) alpha_p[ja * NH + hh] = wa;
        }
        sum += wa;
        const h4 va = X[(size_t)sa * 32 + cl];
        const float2 la = __half22float2(va.a), ma = __half22float2(va.b);
        A0.x = fmaf(wa, la.x, A0.x); A0.y = fmaf(wa, la.y, A0.y);
        A0.z = fmaf(wa, ma.x, A0.z); A0.w = fmaf(wa, ma.y, A0.w);
    }
    // merge halves' partial sums, then normalize
    sum += __shfl_xor(sum, 32, 64);
    const float inv = 1.f / (sum + 1e-30f);
    if (writer && half == 0) inv_s[n * NH + hh] = inv;

    float4 t;
    t.x = A0.x + A1.x; t.y = A0.y + A1.y; t.z = A0.z + A1.z; t.w = A0.w + A1.w;
    t.x += __shfl_xor(t.x, 32, 64);
    t.y += __shfl_xor(t.y, 32, 64);
    t.z += __shfl_xor(t.z, 32, 64);
    t.w += __shfl_xor(t.w, 32, 64);
    t.x *= inv; t.y *= inv; t.z *= inv; t.w *= inv;
    #pragma unroll
    for (int q = 0; q < 2; ++q) {
        const int msk = (q == 0) ? 8 : 16;
        t.x += __shfl_xor(t.x, msk, 64);
        t.y += __shfl_xor(t.y, msk, 64);
        t.z += __shfl_xor(t.z, msk, 64);
        t.w += __shfl_xor(t.w, msk, 64);
    }
    if (lane < 8) {
        const float4 b = ((const float4*)bias)[lane];
        float4 o;
        o.x = t.x * 0.25f + b.x; o.y = t.y * 0.25f + b.y;
        o.z = t.z * 0.25f + b.z; o.w = t.w * 0.25f + b.w;
        ((float4*)out)[(size_t)n * 8 + lane] = o;
    }
}

// ================= kernels =================

__global__ __launch_bounds__(256) void pack_w1_k(const float* __restrict__ mW1,
                                                 float* __restrict__ W1pq) {
    const int idx = blockIdx.x * 256 + threadIdx.x;
    if (idx >= 32 * 128) return;
    const int k = idx >> 7, j = idx & 127;
    W1pq[idx] = (j < 64) ? mW1[k * 64 + j] : mW1[(36 + k) * 64 + (j - 64)];
}

// ---- multi-block exclusive scan (3 phases; HW-verified logic) ----
__global__ __launch_bounds__(256) void scan1_k(const int* __restrict__ deg,
                                               int* __restrict__ bsum) {
    __shared__ int sw[4];
    const int tid = threadIdx.x, lane = tid & 63, wv = tid >> 6;
    const int i = blockIdx.x * 256 + tid;
    int s = (i < NN) ? deg[i] : 0;
    #pragma unroll
    for (int d = 1; d < 64; d <<= 1) s += __shfl_xor(s, d, 64);
    if (lane == 0) sw[wv] = s;
    __syncthreads();
    if (tid == 0) bsum[blockIdx.x] = sw[0] + sw[1] + sw[2] + sw[3];
}

__global__ __launch_bounds__(256) void scan2_k(const int* __restrict__ bsum,
                                               int* __restrict__ boff) {
    __shared__ int sw[8];
    const int tid = threadIdx.x, lane = tid & 63, wv = tid >> 6;
    int v = (tid < NCH) ? bsum[tid] : 0;
    int incl = v;
    #pragma unroll
    for (int d = 1; d < 64; d <<= 1) {
        int t = __shfl_up(incl, d, 64);
        if (lane >= d) incl += t;
    }
    if (lane == 63) sw[wv] = incl;
    __syncthreads();
    if (wv == 0 && lane < 4) {
        int s4 = sw[lane];
        #pragma unroll
        for (int d = 1; d < 4; d <<= 1) {
            int t = __shfl_up(s4, d, 64);
            if (lane >= d) s4 += t;
        }
        sw[lane + 4] = s4;
    }
    __syncthreads();
    const int woff = (wv > 0) ? sw[wv - 1 + 4] : 0;
    if (tid < NCH) boff[tid] = woff + incl - v;
}

__global__ __launch_bounds__(256) void scan3_k(const int* __restrict__ deg,
                                               const int* __restrict__ boff,
                                               int* __restrict__ rowptr,
                                               int* __restrict__ cursor) {
    __shared__ int sw[8];
    const int tid = threadIdx.x, lane = tid & 63, wv = tid >> 6;
    const int c = blockIdx.x;
    const int i = c * 256 + tid;
    int v = (i < NN) ? deg[i] : 0;
    int incl = v;
    #pragma unroll
    for (int d = 1; d < 64; d <<= 1) {
        int t = __shfl_up(incl, d, 64);
        if (lane >= d) incl += t;
    }
    if (lane == 63) sw[wv] = incl;
    __syncthreads();
    if (wv == 0 && lane < 4) {
        int s4 = sw[lane];
        #pragma unroll
        for (int d = 1; d < 4; d <<= 1) {
            int t = __shfl_up(s4, d, 64);
            if (lane >= d) s4 += t;
        }
        sw[lane + 4] = s4;
    }
    __syncthreads();
    const int excl = boff[c] + ((wv > 0) ? sw[wv - 1 + 4] : 0) + incl - v;
    if (i < NN) { rowptr[i] = excl; cursor[i] = excl; }
    if (c == 0 && tid == 0) rowptr[NN] = EE;
}

// scatter: 2 scattered stores per edge (int2{src,dst} + perm) instead of 3
__global__ __launch_bounds__(256) void scatter_perm_k(const int* __restrict__ ei,
                                                      int* __restrict__ cursor,
                                                      int* __restrict__ perm,
                                                      int2* __restrict__ psd) {
    const int e = blockIdx.x * 256 + threadIdx.x;
    if (e >= EE) return;
    const int sv = ei[e];
    const int dv = ei[EE + e];
    const int p = atomicAdd(&cursor[dv], 1);
    perm[p] = e;
    psd[p] = make_int2(sv, dv);
}

__global__ __launch_bounds__(256) void softagg1h_k(const int* __restrict__ rowptr,
                                                   const int2* __restrict__ psd,
                                                   const float* __restrict__ a_s,
                                                   const float* __restrict__ a_d,
                                                   const __half* __restrict__ xl,
                                                   const float* __restrict__ bias,
                                                   float* __restrict__ out) {
    const int n = blockIdx.x * 4 + (threadIdx.x >> 6);
    if (n >= NN) return;
    softagg1_node(n, threadIdx.x & 63, rowptr, psd, a_s, a_d, xl, bias, out);
}

__global__ __launch_bounds__(256) void softagg2h_k(const int* __restrict__ rowptr,
                                                   const int2* __restrict__ psd,
                                                   const float* __restrict__ a_s,
                                                   const float* __restrict__ a_d,
                                                   float* __restrict__ alpha_p,
                                                   float* __restrict__ inv_s,
                                                   const __half* __restrict__ xl,
                                                   const float* __restrict__ bias,
                                                   float* __restrict__ out) {
    const int n = blockIdx.x * 4 + (threadIdx.x >> 6);
    if (n >= NN) return;
    softagg2_node(n, threadIdx.x & 63, rowptr, psd, a_s, a_d, alpha_p, inv_s, xl, bias, out);
}

__global__ __launch_bounds__(256) void edge_mlp_k(const __half* __restrict__ PQ,
                                                  const float* __restrict__ alpha_p,
                                                  const float* __restrict__ inv_s,
                                                  const int2* __restrict__ psd,
                                                  const int* __restrict__ perm,
                                                  const float* __restrict__ mW1,
                                                  const float* __restrict__ mb1,
                                                  const float* __restrict__ mW2,
                                                  const float* __restrict__ mb2,
                                                  float* __restrict__ out) {
    const int lane = threadIdx.x & 63, wvv = threadIdx.x >> 6;
    const int g = lane >> 4, c = lane & 15;

    const float4 wa0 = *(const float4*)&mW1[32 * 64 + c * 4];
    const float4 wa1 = *(const float4*)&mW1[33 * 64 + c * 4];
    const float4 wa2 = *(const float4*)&mW1[34 * 64 + c * 4];
    const float4 wa3 = *(const float4*)&mW1[35 * 64 + c * 4];
    const float4 b1v = *(const float4*)&mb1[c * 4];
    const float4 w2a = *(const float4*)&mW2[c * 8];
    const float4 w2b = *(const float4*)&mW2[c * 8 + 4];
    const float bo0 = mb2[0], bo1 = mb2[1];

    const h4* PQ4 = (const h4*)PQ;
    const int gw = blockIdx.x * 4 + wvv;
    const int stride4 = gridDim.x * 4 * 4;

    for (int jb = gw * 4; jb < EE; jb += stride4) {
        const int j = jb + g;
        const int2 sd = psd[j];
        const int s = sd.x;
        const int d = sd.y;
        const float4 ar = *(const float4*)&alpha_p[(size_t)j * 4];
        const float4 iv = *(const float4*)&inv_s[(size_t)d * 4];
        const float al0 = ar.x * iv.x, al1 = ar.y * iv.y;
        const float al2 = ar.z * iv.z, al3 = ar.w * iv.w;
        const h4 ph = PQ4[(size_t)s * 32 + c];
        const h4 qh = PQ4[(size_t)d * 32 + 16 + c];
        const float2 pl = __half22float2(ph.a), pm = __half22float2(ph.b);
        const float2 ql = __half22float2(qh.a), qm = __half22float2(qh.b);
        float4 h;
        h.x = pl.x + ql.x + b1v.x; h.y = pl.y + ql.y + b1v.y;
        h.z = pm.x + qm.x + b1v.z; h.w = pm.y + qm.y + b1v.w;
        h.x = fmaf(al0, wa0.x, h.x); h.y = fmaf(al0, wa0.y, h.y);
        h.z = fmaf(al0, wa0.z, h.z); h.w = fmaf(al0, wa0.w, h.w);
        h.x = fmaf(al1, wa1.x, h.x); h.y = fmaf(al1, wa1.y, h.y);
        h.z = fmaf(al1, wa1.z, h.z); h.w = fmaf(al1, wa1.w, h.w);
        h.x = fmaf(al2, wa2.x, h.x); h.y = fmaf(al2, wa2.y, h.y);
        h.z = fmaf(al2, wa2.z, h.z); h.w = fmaf(al2, wa2.w, h.w);
        h.x = fmaf(al3, wa3.x, h.x); h.y = fmaf(al3, wa3.y, h.y);
        h.z = fmaf(al3, wa3.z, h.z); h.w = fmaf(al3, wa3.w, h.w);
        h.x = fmaxf(h.x, 0.f); h.y = fmaxf(h.y, 0.f);
        h.z = fmaxf(h.z, 0.f); h.w = fmaxf(h.w, 0.f);

        float v0 = h.x * w2a.x + h.y * w2a.z + h.z * w2b.x + h.w * w2b.z;
        float v1 = h.x * w2a.y + h.y * w2a.w + h.z * w2b.y + h.w * w2b.w;
        #pragma unroll
        for (int msk = 1; msk < 16; msk <<= 1) {
            v0 += __shfl_xor(v0, msk, 64);
            v1 += __shfl_xor(v1, msk, 64);
        }
        if (c == 0)
            *(float2*)&out[(size_t)perm[j] * 2] = make_float2(v0 + bo0, v1 + bo1);
    }
}

extern "C" void kernel_launch(void* const* d_in, const int* in_sizes, int n_in,
                              void* d_out, int out_size, void* d_ws, size_t ws_size,
                              hipStream_t stream) {
    const float* x        = (const float*)d_in[0];
    const int*   ei       = (const int*)d_in[1];
    // d_in[2] edge_attr: unused (edge_dim=None). d_in[3] flag: unused.
    const float* W1       = (const float*)d_in[4];
    const float* att1_src = (const float*)d_in[5];
    const float* att1_dst = (const float*)d_in[6];
    const float* b1       = (const float*)d_in[7];
    const float* W3       = (const float*)d_in[8];
    const float* att3_src = (const float*)d_in[9];
    const float* att3_dst = (const float*)d_in[10];
    const float* b3       = (const float*)d_in[11];
    const float* mW1      = (const float*)d_in[12];
    const float* mb1      = (const float*)d_in[13];
    const float* mW2      = (const float*)d_in[14];
    const float* mb2      = (const float*)d_in[15];

    float* out_nodes = (float*)d_out;               // [N,32]
    float* out_edges = out_nodes + (size_t)NN * 32; // [E,2]

    // workspace layout (floats/ints)
    float* ws = (float*)d_ws;
    __half*   xlh     = (__half*)ws;                  // N*256 halves (layer-1 GEMM out)
    __half*   xl2h    = (__half*)ws;                  // N*128 halves (layer-2 GEMM out)
    __half*   PQh     = (__half*)ws;                  // N*128 halves, after xl2h dead
    float*    h1      = ws + 12800000;                // N*64
    float*    alpha_p = ws + 16000000;                // E*4 (CSR-order raw w, layer 2)
    float*    a_s     = ws + 25600000;                // N*4
    float*    a_d     = ws + 25800000;                // N*4
    float*    W1pq    = ws + 26000000;                // 32*128
    float*    inv_s   = ws + 26100000;                // N*4
    int*      bsum    = (int*)(ws + 26300000);        // NCH
    int*      boff    = (int*)(ws + 26301000);        // NCH
    int*      deg     = (int*)(ws + 26400000);        // N
    int*      cursor  = (int*)(ws + 26450000);        // N
    int*      rowptr  = (int*)(ws + 26500000);        // N+1
    int*      perm    = (int*)(ws + 26550008);        // E
    int2*     psd     = (int2*)(ws + 27350008);       // E (packed {src,dst}, old psrc+pdst)

    const int NB4 = (NN + 3) / 4;

    // 1) CSR build front half
    hipMemsetAsync(deg, 0, (size_t)NN * 4, stream);
    pack_w1_k<<<16, 256, 0, stream>>>(mW1, W1pq);
    // 2) FUSED: count_deg (even blocks) || layer-1 MFMA GEMM (odd blocks), round-robin
    cnt_gemm1_k<<<2 * GR64 * 4, 256, 0, stream>>>(ei, deg, x, W1, xlh,
                                                  att1_src, att1_dst, a_s, a_d);
    // 3) multi-block exclusive scan -> rowptr/cursor
    scan1_k<<<NCH, 256, 0, stream>>>(deg, bsum);
    scan2_k<<<1, 256, 0, stream>>>(bsum, boff);
    scan3_k<<<NCH, 256, 0, stream>>>(deg, boff, rowptr, cursor);
    // 4) scatter edges into CSR order (2 scattered stores/edge)
    scatter_perm_k<<<EB, 256, 0, stream>>>(ei, cursor, perm, psd);
    // 5) layer-1 softmax+aggregate
    softagg1h_k<<<NB4, 256, 0, stream>>>(rowptr, psd, a_s, a_d, xlh, b1, h1);
    // 6) layer-2 GEMM on matrix cores (split-bf16)
    gemm2_mfma_k<<<dim3(GR64, 2), 256, 0, stream>>>(h1, W3, xl2h, att3_src, att3_dst,
                                                    a_s, a_d);
    // 7) layer-2 softmax+aggregate
    softagg2h_k<<<NB4, 256, 0, stream>>>(rowptr, psd, a_s, a_d, alpha_p, inv_s, xl2h, b3,
                                         out_nodes);
    // 8) PQ GEMM on matrix cores (K=32; xl2h dead -> PQh aliases it)
    gemmpq_mfma_k<<<dim3(GR64, 2), 256, 0, stream>>>(out_nodes, W1pq, PQh);
    // 9) edge MLP
    edge_mlp_k<<<2048, 256, 0, stream>>>(PQh, alpha_p, inv_s, psd, perm,
                                         mW1, mb1, mW2, mb2, out_edges);
}